// Round 9
// baseline (495.479 us; speedup 1.0000x reference)
//
#include <hip/hip_runtime.h>
#include <hip/hip_bf16.h>
#include <math.h>

#define S_LEN  2048
#define MDIM   4096
#define NHEADS 32
#define NKV    8
#define HD     128
#define KVDIM  1024
#define NFUSED (MDIM + 2 * KVDIM) /* 6144 */

typedef short bf16x8 __attribute__((ext_vector_type(8)));
typedef float f32x4 __attribute__((ext_vector_type(4)));
typedef float f32x16 __attribute__((ext_vector_type(16)));

__device__ __forceinline__ unsigned short f2b(float f) {
  union { float f; unsigned int u; } v; v.f = f;
  unsigned int r = v.u + 0x7FFFu + ((v.u >> 16) & 1u);
  return (unsigned short)(r >> 16);
}
__device__ __forceinline__ float b2f(unsigned short h) {
  union { unsigned int u; float f; } v; v.u = ((unsigned int)h) << 16;
  return v.f;
}

// async global->LDS, 16B per lane; lds dest = wave-uniform base + lane*16
__device__ __forceinline__ void async_copy16(const void* g, void* l) {
  __builtin_amdgcn_global_load_lds(
      (const __attribute__((address_space(1))) unsigned int*)g,
      (__attribute__((address_space(3))) unsigned int*)l, 16, 0, 0);
}

// ---------------------------------------------------------------------------
// x f32 -> bf16 (one thread per 8 elements)
// ---------------------------------------------------------------------------
__global__ __launch_bounds__(256) void convert_x(
    const float* __restrict__ src, unsigned short* __restrict__ dst) {
  size_t i = (size_t)blockIdx.x * 256 + threadIdx.x;
  const float4 a = ((const float4*)src)[2 * i];
  const float4 b = ((const float4*)src)[2 * i + 1];
  unsigned short o[8] = {f2b(a.x), f2b(a.y), f2b(a.z), f2b(a.w),
                         f2b(b.x), f2b(b.y), f2b(b.z), f2b(b.w)};
  *(int4*)(dst + 8 * i) = *(const int4*)o;
}

// ---------------------------------------------------------------------------
// RoPE table: rtab[s*64+d] = (cos, sin)(s * 50000^(-d/64)). One-time, ~4us.
// ---------------------------------------------------------------------------
__global__ __launch_bounds__(256) void rope_table(float2* __restrict__ rtab) {
  int t = blockIdx.x * 256 + threadIdx.x;  // 0..131071
  int s = t >> 6, d = t & 63;
  float inv_freq = __expf(-0.16905903569f * (float)d);  // 50000^(-d/64)
  float ang = (float)s * inv_freq;
  rtab[t] = make_float2(cosf(ang), sinf(ang));
}

// ---------------------------------------------------------------------------
// Transpose + convert: W [K][N] f32 -> WT [N][K] bf16. 64x64 tiles.
// ---------------------------------------------------------------------------
__global__ __launch_bounds__(256) void transpose_convert(
    const float* __restrict__ W, unsigned short* __restrict__ WT, int K,
    int N) {
  __shared__ unsigned short t[64 * 72];  // [n][k], pad 64->72
  const int k0 = blockIdx.y << 6, n0 = blockIdx.x << 6;
  const int tid = threadIdx.x;
#pragma unroll
  for (int it = 0; it < 4; ++it) {
    int idx = it * 256 + tid;          // 0..1023
    int r = idx & 63;                  // k row
    int c = ((idx >> 6) & 15) << 2;    // n col group
    const float4 v = *(const float4*)(W + (size_t)(k0 + r) * N + n0 + c);
    t[(c + 0) * 72 + r] = f2b(v.x);
    t[(c + 1) * 72 + r] = f2b(v.y);
    t[(c + 2) * 72 + r] = f2b(v.z);
    t[(c + 3) * 72 + r] = f2b(v.w);
  }
  __syncthreads();
  const int n = tid >> 2, kk = (tid & 3) << 4;
  *(int4*)(WT + (size_t)(n0 + n) * K + k0 + kk) = *(int4*)&t[n * 72 + kk];
  *(int4*)(WT + (size_t)(n0 + n) * K + k0 + kk + 8) =
      *(int4*)&t[n * 72 + kk + 8];
}

// ---------------------------------------------------------------------------
// GEMM1: fused = xb[2048][4096](bf16) * WT^T + bqkv, RoPE + head-split.
//
// GEOMETRY FIX (round 8): the 256x256 kernel had grid 24x8 = 192 blocks on
// 256 CUs (25% idle) and 128KiB LDS = 1 block/CU, so the LDS pipe
// (~2800cyc/K-tile) and MFMA pipe (~2066cyc) serialized (observed 4650cyc,
// 124us across 16x16 AND 32x32 shapes and 3 schedule rewrites). New:
// 128x128 tile, BK=64, 4 waves (2x2, 64x64/wave), LDS 64KiB -> 2 blocks/CU,
// grid 48x16 = 768 blocks. Full chip fill + cross-block drift overlaps the
// two pipes (flash's 2-block/CU structure and m97's 3-block/CU both show
// this overlap happening implicitly).
//
// Hash swizzle carried over (rows still 128B): hash(row)=(row^(row>>3))&7.
// Staging: dest row = c*32 + wave*8 + lr8 -> hash = lr8^wave^((c&1)<<2)
// (4c mod 8 = 4(c&1)); pre-swizzled source chunk = lc8 ^ hash. Read: row =
// wrow*64 + i*32 + l31 -> hash = base ^ (i?4:0), base = (l31&7)^(l31>>3);
// even/odd i (jj) use chunk co / co^32 (r7-verified, conflicts 229K).
// C/D: col=lane&31, row=(reg&3)+8*(reg>>2)+4*(lane>>5) [m74/m101].
// acc = f32x16[2][2] (64 f32/lane — no spill; r4 lesson: >128 spills).
// Epilogue: single 128-col slot per block (r0-verified 256-thread code).
// ---------------------------------------------------------------------------
__global__ __launch_bounds__(256, 2) void gemm1_kernel(
    const unsigned short* __restrict__ xb,
    const unsigned short* __restrict__ WT, const float* __restrict__ bias,
    const float2* __restrict__ rtab, unsigned short* __restrict__ Qb,
    unsigned short* __restrict__ Kb, unsigned short* __restrict__ Vt) {
  // [slot][ A 128x64 | B 128x64 ] bf16 = 2 x 32KiB = 64KiB
  __shared__ unsigned short sm[2][16384];

  const int tid = threadIdx.x;
  const int bn = blockIdx.x, bm = blockIdx.y;  // bn: slot 0..47, bm: M/128
  const int lane = tid & 63, wave = tid >> 6;  // 4 waves
  const int l31 = lane & 31, lh = lane >> 5;
  const int wrow = wave >> 1, wcol = wave & 1;  // 2M x 2N wave grid

  f32x16 acc[2][2];
#pragma unroll
  for (int i = 0; i < 2; ++i)
#pragma unroll
    for (int j = 0; j < 2; ++j)
#pragma unroll
      for (int r = 0; r < 16; ++r) acc[i][j][r] = 0.f;

  // staging: copy c covers rows [c*32 + wave*8, +8); lane -> (row lr8,
  // phys chunk lc8). hash(destrow) = lr8 ^ wave ^ ((c&1)<<2).
  const int lr8 = lane >> 3, lc8 = lane & 7;
  const unsigned short* sA =
      xb + (size_t)(bm * 128 + wave * 8 + lr8) * MDIM;  // + c*32*MDIM
  const unsigned short* sB = WT + (size_t)(bn * 128 + wave * 8 + lr8) * MDIM;
  const int swz0 = lc8 ^ lr8 ^ wave;  // chunk pre-swizzle, ^((c&1)<<2) per c

  auto stage = [&](int slot, int k0) {
#pragma unroll
    for (int c = 0; c < 4; ++c) {
      const int chk = (swz0 ^ ((c & 1) << 2)) << 3;
      async_copy16(sA + (size_t)c * 32 * MDIM + k0 + chk,
                   &sm[slot][(c * 32 + wave * 8) * 64]);
      async_copy16(sB + (size_t)c * 32 * MDIM + k0 + chk,
                   &sm[slot][8192 + (c * 32 + wave * 8) * 64]);
    }
  };

  // fragment-read invariants
  const int arow0 = wrow * 64 + l31;  // + i*32
  const int brow0 = wcol * 64 + l31;  // + jj*32
  const int base = (l31 & 7) ^ (l31 >> 3);

  stage(0, 0);  // prologue: K-tile 0 -> slot 0

  for (int kt = 0; kt < 64; ++kt) {
    const int p = kt & 1;
    // own 8 copies of tile kt are the only outstanding VMEM ops; each wave
    // drains ITS copies before the barrier => after barrier all landed.
    asm volatile("s_waitcnt vmcnt(0)" ::: "memory");
    __builtin_amdgcn_s_barrier();  // also: all waves done reading slot p^1
    __builtin_amdgcn_sched_barrier(0);

    if (kt < 63) stage(p ^ 1, (kt + 1) << 6);  // flies under this compute

    const unsigned short* Asl = &sm[p][0];
    const unsigned short* Bsl = &sm[p][8192];
    __builtin_amdgcn_s_setprio(1);
#pragma unroll
    for (int t = 0; t < 4; ++t) {  // k-step of 16
      const int coE = (((2 * t + lh) ^ base) << 3);  // even i/jj rows
      const int coO = coE ^ 32;                      // odd  i/jj rows
      bf16x8 bfr[2], af[2];
      bfr[0] = *(const bf16x8*)&Bsl[(brow0) * 64 + coE];
      bfr[1] = *(const bf16x8*)&Bsl[(brow0 + 32) * 64 + coO];
      af[0] = *(const bf16x8*)&Asl[(arow0) * 64 + coE];
      af[1] = *(const bf16x8*)&Asl[(arow0 + 32) * 64 + coO];
#pragma unroll
      for (int i = 0; i < 2; ++i)
#pragma unroll
        for (int jj = 0; jj < 2; ++jj)
          acc[i][jj] = __builtin_amdgcn_mfma_f32_32x32x16_bf16(
              af[i], bfr[jj], acc[i][jj], 0, 0, 0);
    }
    __builtin_amdgcn_s_setprio(0);
  }
  __syncthreads();  // K-loop reads done before Ct overwrites staging LDS

  // ---- epilogue: Ct[128][132] (33792B, overlays both sm slots) ----
  unsigned short* Ct = &sm[0][0];
  const int slot = bn;  // 0..31 Q, 32..39 K, 40..47 V
#pragma unroll
  for (int i = 0; i < 2; ++i)
#pragma unroll
    for (int jj = 0; jj < 2; ++jj) {
      int lc = wcol * 64 + jj * 32 + l31;
      float bv = bias[slot * 128 + lc];
#pragma unroll
      for (int r = 0; r < 16; ++r) {
        int lrw = wrow * 64 + i * 32 + (r & 3) + 8 * (r >> 2) + 4 * lh;
        Ct[lrw * 132 + lc] = f2b(acc[i][jj][r] + bv);
      }
    }
  __syncthreads();

  if (slot < 40) {
#pragma unroll 4
    for (int it = 0; it < 32; ++it) {
      int row = it * 4 + wave;  // 0..127
      int d = lane;
      float x1 = b2f(Ct[row * 132 + d]);
      float x2 = b2f(Ct[row * 132 + d + 64]);
      int s = bm * 128 + row;
      float2 cs = rtab[s * 64 + d];  // (cos, sin) precomputed
      float o1 = x1 * cs.x - x2 * cs.y;
      float o2 = x2 * cs.x + x1 * cs.y;
      unsigned short* dst;
      if (slot < 32)
        dst = Qb + ((size_t)slot * S_LEN + s) * HD;
      else
        dst = Kb + ((size_t)(slot - 32) * S_LEN + s) * HD;
      dst[d] = f2b(o1);
      dst[d + 64] = f2b(o2);
    }
  } else {
    // V: write transposed Vt[g][d][s], coalesced along s
    const int g = slot - 40;
    unsigned short* Vtg = Vt + (size_t)g * HD * S_LEN;  // [128][2048]
    const int dp = tid >> 2;         // d-pair 0..63
    const int sq = (tid & 3) << 5;   // s-quarter 0,32,64,96
    unsigned short buf0[32], buf1[32];
#pragma unroll
    for (int i = 0; i < 32; ++i) {
      unsigned int w = *(const unsigned int*)&Ct[(sq + i) * 132 + 2 * dp];
      buf0[i] = (unsigned short)(w & 0xffffu);
      buf1[i] = (unsigned short)(w >> 16);
    }
    const int s0 = bm * 128 + sq;
#pragma unroll
    for (int c = 0; c < 2; ++c) {
      unsigned short* dst = Vtg + (size_t)(2 * dp + c) * S_LEN + s0;
      const unsigned short* b = c ? buf1 : buf0;
#pragma unroll
      for (int q4 = 0; q4 < 4; ++q4)
        *(int4*)(dst + q4 * 8) = *(const int4*)(b + q4 * 8);
    }
  }
}

// ---------------------------------------------------------------------------
// GEMM2: out = attnb[2048][4096](bf16) * WoT^T + bo (f32 out).
// BM=128 x BN=256 (grid 16x16 = 256 blocks = 1/CU), BK=64, 8 waves (2M x 4N,
// 64x64 per wave), dbuf 96KiB LDS, 32x32x16 MFMA, single barrier per K-tile.
// Generalized hash swizzle (r7).
// ---------------------------------------------------------------------------
__global__ __launch_bounds__(512, 2) void gemm2_kernel(
    const unsigned short* __restrict__ Ab16,
    const unsigned short* __restrict__ BT, const float* __restrict__ bias,
    float* __restrict__ C) {
  // [slot][ A 128x64 | B 256x64 ] bf16 = 2 x 48KiB = 96KiB
  __shared__ unsigned short sm[2][24576];

  const int tid = threadIdx.x;
  const int bn = blockIdx.x, bm = blockIdx.y;  // bn: N/256, bm: M/128
  const int lane = tid & 63, wave = tid >> 6;
  const int l31 = lane & 31, lh = lane >> 5;
  const int wrow = wave >> 2, wcol = wave & 3;  // 2M x 4N wave grid

  f32x16 acc[2][2];
#pragma unroll
  for (int i = 0; i < 2; ++i)
#pragma unroll
    for (int j = 0; j < 2; ++j)
#pragma unroll
      for (int r = 0; r < 16; ++r) acc[i][j][r] = 0.f;

  const int lr8 = lane >> 3, lc8 = lane & 7;
  const int baser = wave * 8 + lr8;
  const size_t swz = (size_t)((lc8 ^ lr8 ^ wave) << 3);
  const unsigned short* sA = Ab16 + (size_t)(bm * 128 + baser) * MDIM + swz;
  const unsigned short* sB = BT + (size_t)(bn * 256 + baser) * MDIM + swz;

  auto stage = [&](int slot, int k0) {
#pragma unroll
    for (int c = 0; c < 2; ++c)
      async_copy16(sA + (size_t)c * 64 * MDIM + k0,
                   &sm[slot][(c * 64 + wave * 8) * 64]);
#pragma unroll
    for (int c = 0; c < 4; ++c)
      async_copy16(sB + (size_t)c * 64 * MDIM + k0,
                   &sm[slot][8192 + (c * 64 + wave * 8) * 64]);
  };

  const int arow0 = wrow * 64 + l31;  // + i*32
  const int brow0 = wcol * 64 + l31;  // + jj*32
  const int base = (l31 & 7) ^ (l31 >> 3);

  stage(0, 0);  // prologue: K-tile 0 -> slot 0

#pragma unroll 1
  for (int kt = 0; kt < 64; ++kt) {
    const int p = kt & 1;
    asm volatile("s_waitcnt vmcnt(0)" ::: "memory");
    __builtin_amdgcn_s_barrier();
    __builtin_amdgcn_sched_barrier(0);

    if (kt < 63) stage(p ^ 1, (kt + 1) << 6);

    const unsigned short* Asl = &sm[p][0];
    const unsigned short* Bsl = &sm[p][8192];
    __builtin_amdgcn_s_setprio(1);
#pragma unroll
    for (int t = 0; t < 4; ++t) {
      const int coE = (((2 * t + lh) ^ base) << 3);
      const int coO = coE ^ 32;
      bf16x8 bfr[2], af[2];
      bfr[0] = *(const bf16x8*)&Bsl[(brow0) * 64 + coE];
      bfr[1] = *(const bf16x8*)&Bsl[(brow0 + 32) * 64 + coO];
      af[0] = *(const bf16x8*)&Asl[(arow0) * 64 + coE];
      af[1] = *(const bf16x8*)&Asl[(arow0 + 32) * 64 + coO];
#pragma unroll
      for (int i = 0; i < 2; ++i)
#pragma unroll
        for (int jj = 0; jj < 2; ++jj)
          acc[i][jj] = __builtin_amdgcn_mfma_f32_32x32x16_bf16(
              af[i], bfr[jj], acc[i][jj], 0, 0, 0);
    }
    __builtin_amdgcn_s_setprio(0);
  }

  // epilogue: direct f32 store with bias
#pragma unroll
  for (int i = 0; i < 2; ++i)
#pragma unroll
    for (int jj = 0; jj < 2; ++jj) {
      int gcol = bn * 256 + wcol * 64 + jj * 32 + l31;
      float bv = bias[gcol];
#pragma unroll
      for (int r = 0; r < 16; ++r) {
        int grow =
            bm * 128 + wrow * 64 + i * 32 + (r & 3) + 8 * (r >> 2) + 4 * lh;
        C[(size_t)grow * MDIM + gcol] = acc[i][jj][r] + bv;
      }
    }
}

// ---------------------------------------------------------------------------
// Flash attention, causal, GQA. Fixed-max softmax (scores bounded; exp(s-12)
// cannot overflow, o/l unchanged). Q in registers. K/V double-buffered LDS
// via global_load_lds with XOR-swizzled layout (pre-swizzled global source,
// linear LDS dest). One vmcnt(0)+barrier per KV-tile; prefetch issued after
// the barrier flies under the whole compute phase. Ps fence: lgkmcnt only.
// Row-sums via ones-MFMA. 1D LPT grid.
// ---------------------------------------------------------------------------
__device__ __forceinline__ void stage_kv(const unsigned short* __restrict__ Kg,
                                         const unsigned short* __restrict__ Vg,
                                         int jtile, unsigned short* KsBuf,
                                         unsigned short* VsBuf, int wv,
                                         int lane) {
  const unsigned short* kg = Kg + (size_t)jtile * 64 * HD;
  const unsigned short* vg = Vg + jtile * 64;
#pragma unroll
  for (int it = 0; it < 4; ++it) {
    // K: 4 rows x 256B per copy; lane -> row base+(l>>4), chunk l&15
    int kr = wv * 16 + it * 4 + (lane >> 4);
    async_copy16(kg + (size_t)kr * HD + (((lane & 15) ^ (kr & 7)) << 3),
                 KsBuf + (wv * 16 + it * 4) * 128);
    // V: 8 rows x 128B per copy; lane -> row base+(l>>3), chunk l&7
    int vr = wv * 32 + it * 8 + (lane >> 3);
    async_copy16(vg + (size_t)vr * S_LEN + (((lane & 7) ^ (vr & 7)) << 3),
                 VsBuf + (wv * 32 + it * 8) * 64);
  }
}

__global__ __launch_bounds__(256, 2) void flash_kernel(
    const unsigned short* __restrict__ Qb, const unsigned short* __restrict__ Kb,
    const unsigned short* __restrict__ Vt, unsigned short* __restrict__ attnb) {
  __shared__ __align__(16) unsigned short Ks[2][64 * 128];  // [krow][d] swz
  __shared__ __align__(16) unsigned short Vs[2][128 * 64];  // [d][kvpos] swz
  __shared__ __align__(16) unsigned short Ps[64 * 72];      // [qrow][kvpos]

  const int tid = threadIdx.x;
  const int bid = blockIdx.x;
  const int h = bid & 31;
  const int qt = 31 - (bid >> 5);  // heavy tiles dispatch first (LPT)
  const int g = h >> 2;
  const int wv = tid >> 6, lane = tid & 63;
  const int lrow = lane & 15, quad = lane >> 4;
  const float scale = 0.08838834764831845f;  // 1/sqrt(128)

  const unsigned short* Qg = Qb + ((size_t)h * S_LEN + qt * 64) * HD;
  bf16x8 qf[4];
#pragma unroll
  for (int ks = 0; ks < 4; ++ks)
    qf[ks] = *(const bf16x8*)(Qg + (size_t)(wv * 16 + lrow) * HD + ks * 32 +
                              quad * 8);

  // all-ones bf16 B-fragment for row-sum MFMA
  bf16x8 ones;
#pragma unroll
  for (int i = 0; i < 8; ++i) ones[i] = (short)0x3F80;

  const unsigned short* Kg = Kb + (size_t)g * S_LEN * HD;   // [s][d]
  const unsigned short* Vg = Vt + (size_t)g * HD * S_LEN;   // [d][s]

  f32x4 l_acc = {0.f, 0.f, 0.f, 0.f};
  f32x4 o_acc[8];
#pragma unroll
  for (int jc = 0; jc < 8; ++jc) {
    f32x4 z = {0.f, 0.f, 0.f, 0.f};
    o_acc[jc] = z;
  }

  // prologue: stage tile 0 into buffer 0
  stage_kv(Kg, Vg, 0, &Ks[0][0], &Vs[0][0], wv, lane);

  for (int jt = 0; jt <= qt; ++jt) {
    const int cb = jt & 1;
    // own copies of tile jt are the only outstanding VMEM ops
    asm volatile("s_waitcnt vmcnt(0)" ::: "memory");
    __builtin_amdgcn_s_barrier();  // all waves' copies landed; all waves
                                   // done reading buf cb from iter jt-2
    __builtin_amdgcn_sched_barrier(0);

    if (jt < qt)  // prefetch next tile; flies under this iter's compute
      stage_kv(Kg, Vg, jt + 1, &Ks[cb ^ 1][0], &Vs[cb ^ 1][0], wv, lane);

    // S = Q K^T (wave's 16 rows x 64 cols)
    f32x4 s_acc[4];
#pragma unroll
    for (int j = 0; j < 4; ++j) {
      f32x4 z = {0.f, 0.f, 0.f, 0.f};
      s_acc[j] = z;
    }
#pragma unroll
    for (int ks = 0; ks < 4; ++ks)
#pragma unroll
      for (int j = 0; j < 4; ++j) {
        int row = j * 16 + lrow;
        bf16x8 bk = *(const bf16x8*)&Ks[cb][row * 128 +
                                           (((ks * 4 + quad) ^ (row & 7)) << 3)];
        s_acc[j] = __builtin_amdgcn_mfma_f32_16x16x32_bf16(qf[ks], bk,
                                                           s_acc[j], 0, 0, 0);
      }

    // fixed-max softmax: p = exp(s*scale - 12); mask only on diagonal tile
    if (jt == qt) {
#pragma unroll
      for (int r = 0; r < 4; ++r) {
        int grow = qt * 64 + wv * 16 + quad * 4 + r;
#pragma unroll
        for (int j = 0; j < 4; ++j) {
          int gcol = jt * 64 + j * 16 + lrow;
          float p =
              (gcol <= grow) ? __expf(s_acc[j][r] * scale - 12.0f) : 0.f;
          Ps[(wv * 16 + quad * 4 + r) * 72 + j * 16 + lrow] = f2b(p);
        }
      }
    } else {
#pragma unroll
      for (int r = 0; r < 4; ++r)
#pragma unroll
        for (int j = 0; j < 4; ++j) {
          float p = __expf(s_acc[j][r] * scale - 12.0f);
          Ps[(wv * 16 + quad * 4 + r) * 72 + j * 16 + lrow] = f2b(p);
        }
    }
    // Ps band is wave-private: LDS drain only (must NOT drain vmcnt — the
    // next tile's global_load_lds copies are in flight)
    asm volatile("s_waitcnt lgkmcnt(0)" ::: "memory");
    __builtin_amdgcn_sched_barrier(0);

    // O += P V (16 rows x 128 cols, K=64); l += P * ones
#pragma unroll
    for (int kk = 0; kk < 2; ++kk) {
      bf16x8 ap =
          *(const bf16x8*)&Ps[(wv * 16 + lrow) * 72 + kk * 32 + 8 * quad];
      l_acc = __builtin_amdgcn_mfma_f32_16x16x32_bf16(ap, ones, l_acc, 0, 0, 0);
#pragma unroll
      for (int jc = 0; jc < 8; ++jc) {
        int row = jc * 16 + lrow;
        bf16x8 bv = *(const bf16x8*)&Vs[cb][row * 64 +
                                            (((kk * 4 + quad) ^ (row & 7)) << 3)];
        o_acc[jc] = __builtin_amdgcn_mfma_f32_16x16x32_bf16(ap, bv, o_acc[jc],
                                                            0, 0, 0);
      }
    }
    __builtin_amdgcn_s_barrier();  // all waves done reading buf cb before
                                   // iter jt+1 issues copies into buf cb
  }

  // epilogue: O / l -> attnb[s][h*128+d] (bf16)
#pragma unroll
  for (int r = 0; r < 4; ++r) {
    float inv_l = 1.0f / l_acc[r];
    int row = qt * 64 + wv * 16 + quad * 4 + r;
#pragma unroll
    for (int jc = 0; jc < 8; ++jc) {
      int col = jc * 16 + lrow;
      attnb[(size_t)row * MDIM + h * HD + col] = f2b(o_acc[jc][r] * inv_l);
    }
  }
}

// ---------------------------------------------------------------------------
extern "C" void kernel_launch(void* const* d_in, const int* in_sizes, int n_in,
                              void* d_out, int out_size, void* d_ws,
                              size_t ws_size, hipStream_t stream) {
  const float* x = (const float*)d_in[0];
  const float* Wqkv = (const float*)d_in[1];
  const float* bqkv = (const float*)d_in[2];
  const float* Wo = (const float*)d_in[3];
  const float* bo = (const float*)d_in[4];
  float* out = (float*)d_out;

  unsigned char* ws = (unsigned char*)d_ws;
  // region A [0, 50331648): phase1 = WT (6144x4096 bf16);
  //                         phase2 = WoT (33554432) + attnb (16777216)
  unsigned short* WT = (unsigned short*)ws;
  unsigned short* WoT = (unsigned short*)ws;
  unsigned short* attnb = (unsigned short*)(ws + 33554432);
  // region B: Q/K head-major bf16, V transposed [g][d][s]
  unsigned short* Qb = (unsigned short*)(ws + 50331648);  // 32*2048*128
  unsigned short* Kb = (unsigned short*)(ws + 67108864);  // 8*2048*128
  unsigned short* Vt = (unsigned short*)(ws + 71303168);  // 8*128*2048
  // d_out scratch: xb (bf16 x) in [0,16MB); RoPE table in [16MB,17MB).
  // Both consumed before gemm2 overwrites d_out with the final output.
  unsigned short* xb = (unsigned short*)d_out;
  float2* rtab = (float2*)((unsigned char*)d_out + 16777216);

  // 0. x f32 -> bf16 (into d_out scratch) + RoPE cos/sin table
  convert_x<<<(S_LEN * MDIM / 8) / 256, 256, 0, stream>>>(x, xb);
  rope_table<<<(S_LEN * 64) / 256, 256, 0, stream>>>(rtab);
  // 1. Wqkv [4096][6144] f32 -> WT [6144][4096] bf16
  transpose_convert<<<dim3(NFUSED / 64, MDIM / 64), 256, 0, stream>>>(
      Wqkv, WT, MDIM, NFUSED);
  // 2. QKV GEMM with fused bias + RoPE + head split (V transposed)
  gemm1_kernel<<<dim3(NFUSED / 128, S_LEN / 128), 256, 0, stream>>>(
      xb, WT, bqkv, rtab, Qb, Kb, Vt);
  // 3. Wo [4096][4096] f32 -> WoT [4096][4096] bf16 (reuses WT region)
  transpose_convert<<<dim3(MDIM / 64, MDIM / 64), 256, 0, stream>>>(Wo, WoT,
                                                                    MDIM, MDIM);
  // 4. causal GQA flash attention -> attnb bf16 (1D LPT grid)
  flash_kernel<<<S_LEN / 64 * NHEADS, 256, 0, stream>>>(Qb, Kb, Vt, attnb);
  // 5. output projection (overwrites xb scratch region of d_out)
  gemm2_kernel<<<dim3(MDIM / 256, S_LEN / 128), 512, 0, stream>>>(attnb, WoT,
                                                                  bo, out);
}

// Round 10
// 484.612 us; speedup vs baseline: 1.0224x; 1.0224x over previous
//
#include <hip/hip_runtime.h>
#include <hip/hip_bf16.h>
#include <math.h>

#define S_LEN  2048
#define MDIM   4096
#define NHEADS 32
#define NKV    8
#define HD     128
#define KVDIM  1024
#define NFUSED (MDIM + 2 * KVDIM) /* 6144 */

typedef short bf16x8 __attribute__((ext_vector_type(8)));
typedef float f32x4 __attribute__((ext_vector_type(4)));
typedef float f32x16 __attribute__((ext_vector_type(16)));

__device__ __forceinline__ unsigned short f2b(float f) {
  union { float f; unsigned int u; } v; v.f = f;
  unsigned int r = v.u + 0x7FFFu + ((v.u >> 16) & 1u);
  return (unsigned short)(r >> 16);
}
__device__ __forceinline__ float b2f(unsigned short h) {
  union { unsigned int u; float f; } v; v.u = ((unsigned int)h) << 16;
  return v.f;
}

// async global->LDS, 16B per lane; lds dest = wave-uniform base + lane*16
__device__ __forceinline__ void async_copy16(const void* g, void* l) {
  __builtin_amdgcn_global_load_lds(
      (const __attribute__((address_space(1))) unsigned int*)g,
      (__attribute__((address_space(3))) unsigned int*)l, 16, 0, 0);
}

// ---------------------------------------------------------------------------
// x f32 -> bf16 (one thread per 8 elements)
// ---------------------------------------------------------------------------
__global__ __launch_bounds__(256) void convert_x(
    const float* __restrict__ src, unsigned short* __restrict__ dst) {
  size_t i = (size_t)blockIdx.x * 256 + threadIdx.x;
  const float4 a = ((const float4*)src)[2 * i];
  const float4 b = ((const float4*)src)[2 * i + 1];
  unsigned short o[8] = {f2b(a.x), f2b(a.y), f2b(a.z), f2b(a.w),
                         f2b(b.x), f2b(b.y), f2b(b.z), f2b(b.w)};
  *(int4*)(dst + 8 * i) = *(const int4*)o;
}

// ---------------------------------------------------------------------------
// RoPE table: rtab[s*64+d] = (cos, sin)(s * 50000^(-d/64)). One-time, ~4us.
// ---------------------------------------------------------------------------
__global__ __launch_bounds__(256) void rope_table(float2* __restrict__ rtab) {
  int t = blockIdx.x * 256 + threadIdx.x;  // 0..131071
  int s = t >> 6, d = t & 63;
  float inv_freq = __expf(-0.16905903569f * (float)d);  // 50000^(-d/64)
  float ang = (float)s * inv_freq;
  rtab[t] = make_float2(cosf(ang), sinf(ang));
}

// ---------------------------------------------------------------------------
// Transpose + convert: W [K][N] f32 -> WT [N][K] bf16. 64x64 tiles.
//
// COALESCING FIX (round 9): the old kernel mapped r = idx&63 -> consecutive
// LANES read consecutive ROWS (float4 at stride N*4B = 24KB apart): 16B
// used per 64B line = 4x HBM over-fetch (~400MB for Wqkv, ~268MB for Wo).
// New: classic padded-f32 transpose. Load row-major coalesced (row=idx>>4,
// 16 contiguous float4 per row). Stage f32 t[64][65]: write bank =
// (row+4cq+j)%32 -> 2-way (free); read bank = (k+n)%32 -> 2-way (free).
// Each thread reads 16 k's of one n-column, converts, stores 2xint4.
// ---------------------------------------------------------------------------
__global__ __launch_bounds__(256) void transpose_convert(
    const float* __restrict__ W, unsigned short* __restrict__ WT, int K,
    int N) {
  __shared__ float t[64 * 65];  // [k][n], pad 64->65 (f32)
  const int k0 = blockIdx.y << 6, n0 = blockIdx.x << 6;
  const int tid = threadIdx.x;
#pragma unroll
  for (int it = 0; it < 4; ++it) {
    int idx = it * 256 + tid;        // 0..1023
    int r = idx >> 4;                // k row 0..63
    int cq = idx & 15;               // float4 col group
    const float4 v =
        *(const float4*)(W + (size_t)(k0 + r) * N + n0 + (cq << 2));
    t[r * 65 + (cq << 2) + 0] = v.x;
    t[r * 65 + (cq << 2) + 1] = v.y;
    t[r * 65 + (cq << 2) + 2] = v.z;
    t[r * 65 + (cq << 2) + 3] = v.w;
  }
  __syncthreads();
  const int n = tid >> 2, kk = (tid & 3) << 4;
  unsigned short o[16];
#pragma unroll
  for (int j = 0; j < 16; ++j) o[j] = f2b(t[(kk + j) * 65 + n]);
  *(int4*)(WT + (size_t)(n0 + n) * K + k0 + kk) = *(const int4*)&o[0];
  *(int4*)(WT + (size_t)(n0 + n) * K + k0 + kk + 8) = *(const int4*)&o[8];
}

// ---------------------------------------------------------------------------
// GEMM1: fused = xb[2048][4096](bf16) * WT^T + bqkv, RoPE + head-split
// epilogue. 256x256 tile, BK=64, 8 waves (2M x 4N), dbuf 128KiB LDS,
// 32x32x16 MFMA, single vmcnt(0)+barrier per K-tile. (round-7 version,
// best measured: 124.5us; round-8's 128² geometry regressed to 134.5.)
//
// Hash swizzle: hash(row) = (row ^ (row>>3)) & 7 (fixes the 4-way conflict
// the 32x32 fragment pattern had with row&7: lanes {x,x+8,x+16,x+24} same
// chunk in rows 8 apart = bank-wrap; verified 9.67M -> 229K conflicts).
// Write: dest row = c*64+wave*8+lr8 -> hash = lr8^wave; source chunk =
// lc8^lr8^wave (constant across c). Read: row = woff + l31 + i*32 -> hash
// = base ^ (i&1?4:0), base = (l31&7)^(l31>>3); even/odd i use co / co^32.
// C/D: col=lane&31, row=(reg&3)+8*(reg>>2)+4*(lane>>5) [m74/m101].
// acc = f32x16[4][2], statically indexed (rule #20).
// ---------------------------------------------------------------------------
__global__ __launch_bounds__(512, 2) void gemm1_kernel(
    const unsigned short* __restrict__ xb,
    const unsigned short* __restrict__ WT, const float* __restrict__ bias,
    const float2* __restrict__ rtab, unsigned short* __restrict__ Qb,
    unsigned short* __restrict__ Kb, unsigned short* __restrict__ Vt) {
  // [slot][ A 256x64 | B 256x64 ] bf16 = 2 x 64KiB = 128KiB
  __shared__ unsigned short sm[2][32768];

  const int tid = threadIdx.x;
  const int bn = blockIdx.x, bm = blockIdx.y;
  const int lane = tid & 63, wave = tid >> 6;
  const int l31 = lane & 31, lh = lane >> 5;
  const int wrow = wave >> 2, wcol = wave & 3;  // 2M x 4N wave grid

  f32x16 acc[4][2];
#pragma unroll
  for (int i = 0; i < 4; ++i)
#pragma unroll
    for (int j = 0; j < 2; ++j)
#pragma unroll
      for (int r = 0; r < 16; ++r) acc[i][j][r] = 0.f;

  // staging: each copy = 64 rows over 8 waves (8 rows/wave); lane ->
  // (row lr8, phys chunk lc8). hash(destrow)=lr8^wave -> src chunk below.
  const int lr8 = lane >> 3, lc8 = lane & 7;
  const int baser = wave * 8 + lr8;                    // tile row (+c*64)
  const size_t swz = (size_t)((lc8 ^ lr8 ^ wave) << 3);  // pre-swizzle
  const unsigned short* sA = xb + (size_t)(bm * 256 + baser) * MDIM + swz;
  const unsigned short* sB = WT + (size_t)(bn * 256 + baser) * MDIM + swz;

  auto stage = [&](int slot, int k0) {
#pragma unroll
    for (int c = 0; c < 4; ++c) {
      unsigned short* dA = &sm[slot][(c * 64 + wave * 8) * 64];
      unsigned short* dB = &sm[slot][16384 + (c * 64 + wave * 8) * 64];
      async_copy16(sA + (size_t)c * 64 * MDIM + k0, dA);
      async_copy16(sB + (size_t)c * 64 * MDIM + k0, dB);
    }
  };

  // fragment-read invariants
  const int arow0 = wrow * 128 + l31;  // + i*32
  const int brow0 = wcol * 64 + l31;   // + jj*32
  const int base = (l31 & 7) ^ (l31 >> 3);

  stage(0, 0);  // prologue: K-tile 0 -> slot 0

  for (int kt = 0; kt < 64; ++kt) {
    const int p = kt & 1;
    // own 8 copies of tile kt are the only outstanding VMEM ops; each wave
    // drains ITS copies before the barrier => after barrier all landed.
    asm volatile("s_waitcnt vmcnt(0)" ::: "memory");
    __builtin_amdgcn_s_barrier();  // also: all waves done reading slot p^1
    __builtin_amdgcn_sched_barrier(0);

    if (kt < 63) stage(p ^ 1, (kt + 1) << 6);  // flies under this compute

    const unsigned short* Asl = &sm[p][0];
    const unsigned short* Bsl = &sm[p][16384];
    __builtin_amdgcn_s_setprio(1);
#pragma unroll
    for (int t = 0; t < 4; ++t) {  // k-step of 16
      const int coE = (((2 * t + lh) ^ base) << 3);  // even i/jj rows
      const int coO = coE ^ 32;                      // odd  i/jj rows (+4 hash)
      bf16x8 bfr[2], af[4];
      bfr[0] = *(const bf16x8*)&Bsl[(brow0) * 64 + coE];
      bfr[1] = *(const bf16x8*)&Bsl[(brow0 + 32) * 64 + coO];
      af[0] = *(const bf16x8*)&Asl[(arow0) * 64 + coE];
      af[1] = *(const bf16x8*)&Asl[(arow0 + 32) * 64 + coO];
      af[2] = *(const bf16x8*)&Asl[(arow0 + 64) * 64 + coE];
      af[3] = *(const bf16x8*)&Asl[(arow0 + 96) * 64 + coO];
#pragma unroll
      for (int i = 0; i < 4; ++i)
#pragma unroll
        for (int jj = 0; jj < 2; ++jj)
          acc[i][jj] = __builtin_amdgcn_mfma_f32_32x32x16_bf16(
              af[i], bfr[jj], acc[i][jj], 0, 0, 0);
    }
    __builtin_amdgcn_s_setprio(0);
  }
  __syncthreads();  // K-loop reads done before Ct overwrites staging LDS

  // ---- epilogue: two 128-col halves; Ct[256][132] reuses staging LDS ----
  unsigned short* Ct = &sm[0][0];
#pragma unroll 1
  for (int h = 0; h < 2; ++h) {
    const int slot = 2 * bn + h;  // 0..31 Q, 32..39 K, 40..47 V
    if ((wcol >> 1) == h) {       // waves owning this col half write acc
#pragma unroll
      for (int i = 0; i < 4; ++i)
#pragma unroll
        for (int jj = 0; jj < 2; ++jj) {
          int lc = (wcol & 1) * 64 + jj * 32 + l31;
          float bv = bias[slot * 128 + lc];
#pragma unroll
          for (int r = 0; r < 16; ++r) {
            int lrw = wrow * 128 + i * 32 + (r & 3) + 8 * (r >> 2) + 4 * lh;
            Ct[lrw * 132 + lc] = f2b(acc[i][jj][r] + bv);
          }
        }
    }
    __syncthreads();

    if (slot < 40) {
#pragma unroll 4
      for (int it = 0; it < 32; ++it) {
        int row = it * 8 + wave;  // 0..255
        int d = lane;
        float x1 = b2f(Ct[row * 132 + d]);
        float x2 = b2f(Ct[row * 132 + d + 64]);
        int s = bm * 256 + row;
        float2 cs = rtab[s * 64 + d];  // (cos, sin) precomputed
        float o1 = x1 * cs.x - x2 * cs.y;
        float o2 = x2 * cs.x + x1 * cs.y;
        unsigned short* dst;
        if (slot < 32)
          dst = Qb + ((size_t)slot * S_LEN + s) * HD;
        else
          dst = Kb + ((size_t)(slot - 32) * S_LEN + s) * HD;
        dst[d] = f2b(o1);
        dst[d + 64] = f2b(o2);
      }
    } else {
      // V: write transposed Vt[g][d][s], coalesced along s
      const int g = slot - 40;
      unsigned short* Vtg = Vt + (size_t)g * HD * S_LEN;  // [128][2048]
      const int dp = tid >> 3;         // d-pair 0..63
      const int sq = (tid & 7) << 5;   // s-eighth 0,32,..,224
      unsigned short buf0[32], buf1[32];
#pragma unroll
      for (int i = 0; i < 32; ++i) {
        unsigned int w = *(const unsigned int*)&Ct[(sq + i) * 132 + 2 * dp];
        buf0[i] = (unsigned short)(w & 0xffffu);
        buf1[i] = (unsigned short)(w >> 16);
      }
      const int s0 = bm * 256 + sq;
#pragma unroll
      for (int c = 0; c < 2; ++c) {
        unsigned short* dst = Vtg + (size_t)(2 * dp + c) * S_LEN + s0;
        const unsigned short* b = c ? buf1 : buf0;
#pragma unroll
        for (int q4 = 0; q4 < 4; ++q4)
          *(int4*)(dst + q4 * 8) = *(const int4*)(b + q4 * 8);
      }
    }
    __syncthreads();  // pass-h reads done before pass h+1 overwrites Ct
  }
}

// ---------------------------------------------------------------------------
// GEMM2: out = attnb[2048][4096](bf16) * WoT^T + bo (f32 out).
// BM=128 x BN=256 (grid 16x16 = 256 blocks = 1/CU), BK=64, 8 waves (2M x 4N,
// 64x64 per wave), dbuf 96KiB LDS, 32x32x16 MFMA, single barrier per K-tile.
// Generalized hash swizzle (r7).
// ---------------------------------------------------------------------------
__global__ __launch_bounds__(512, 2) void gemm2_kernel(
    const unsigned short* __restrict__ Ab16,
    const unsigned short* __restrict__ BT, const float* __restrict__ bias,
    float* __restrict__ C) {
  // [slot][ A 128x64 | B 256x64 ] bf16 = 2 x 48KiB = 96KiB
  __shared__ unsigned short sm[2][24576];

  const int tid = threadIdx.x;
  const int bn = blockIdx.x, bm = blockIdx.y;  // bn: N/256, bm: M/128
  const int lane = tid & 63, wave = tid >> 6;
  const int l31 = lane & 31, lh = lane >> 5;
  const int wrow = wave >> 2, wcol = wave & 3;  // 2M x 4N wave grid

  f32x16 acc[2][2];
#pragma unroll
  for (int i = 0; i < 2; ++i)
#pragma unroll
    for (int j = 0; j < 2; ++j)
#pragma unroll
      for (int r = 0; r < 16; ++r) acc[i][j][r] = 0.f;

  const int lr8 = lane >> 3, lc8 = lane & 7;
  const int baser = wave * 8 + lr8;
  const size_t swz = (size_t)((lc8 ^ lr8 ^ wave) << 3);
  const unsigned short* sA = Ab16 + (size_t)(bm * 128 + baser) * MDIM + swz;
  const unsigned short* sB = BT + (size_t)(bn * 256 + baser) * MDIM + swz;

  auto stage = [&](int slot, int k0) {
#pragma unroll
    for (int c = 0; c < 2; ++c)
      async_copy16(sA + (size_t)c * 64 * MDIM + k0,
                   &sm[slot][(c * 64 + wave * 8) * 64]);
#pragma unroll
    for (int c = 0; c < 4; ++c)
      async_copy16(sB + (size_t)c * 64 * MDIM + k0,
                   &sm[slot][8192 + (c * 64 + wave * 8) * 64]);
  };

  const int arow0 = wrow * 64 + l31;  // + i*32
  const int brow0 = wcol * 64 + l31;  // + jj*32
  const int base = (l31 & 7) ^ (l31 >> 3);

  stage(0, 0);  // prologue: K-tile 0 -> slot 0

#pragma unroll 1
  for (int kt = 0; kt < 64; ++kt) {
    const int p = kt & 1;
    asm volatile("s_waitcnt vmcnt(0)" ::: "memory");
    __builtin_amdgcn_s_barrier();
    __builtin_amdgcn_sched_barrier(0);

    if (kt < 63) stage(p ^ 1, (kt + 1) << 6);

    const unsigned short* Asl = &sm[p][0];
    const unsigned short* Bsl = &sm[p][8192];
    __builtin_amdgcn_s_setprio(1);
#pragma unroll
    for (int t = 0; t < 4; ++t) {
      const int coE = (((2 * t + lh) ^ base) << 3);
      const int coO = coE ^ 32;
      bf16x8 bfr[2], af[2];
      bfr[0] = *(const bf16x8*)&Bsl[(brow0) * 64 + coE];
      bfr[1] = *(const bf16x8*)&Bsl[(brow0 + 32) * 64 + coO];
      af[0] = *(const bf16x8*)&Asl[(arow0) * 64 + coE];
      af[1] = *(const bf16x8*)&Asl[(arow0 + 32) * 64 + coO];
#pragma unroll
      for (int i = 0; i < 2; ++i)
#pragma unroll
        for (int jj = 0; jj < 2; ++jj)
          acc[i][jj] = __builtin_amdgcn_mfma_f32_32x32x16_bf16(
              af[i], bfr[jj], acc[i][jj], 0, 0, 0);
    }
    __builtin_amdgcn_s_setprio(0);
  }

  // epilogue: direct f32 store with bias
#pragma unroll
  for (int i = 0; i < 2; ++i)
#pragma unroll
    for (int jj = 0; jj < 2; ++jj) {
      int gcol = bn * 256 + wcol * 64 + jj * 32 + l31;
      float bv = bias[gcol];
#pragma unroll
      for (int r = 0; r < 16; ++r) {
        int grow =
            bm * 128 + wrow * 64 + i * 32 + (r & 3) + 8 * (r >> 2) + 4 * lh;
        C[(size_t)grow * MDIM + gcol] = acc[i][jj][r] + bv;
      }
    }
}

// ---------------------------------------------------------------------------
// Flash attention, causal, GQA. Fixed-max softmax (scores bounded; exp(s-12)
// cannot overflow, o/l unchanged). Q in registers. K/V double-buffered LDS
// via global_load_lds with XOR-swizzled layout (pre-swizzled global source,
// linear LDS dest). One vmcnt(0)+barrier per KV-tile; prefetch issued after
// the barrier flies under the whole compute phase. Ps fence: lgkmcnt only.
// Row-sums via ones-MFMA. 1D LPT grid.
// ---------------------------------------------------------------------------
__device__ __forceinline__ void stage_kv(const unsigned short* __restrict__ Kg,
                                         const unsigned short* __restrict__ Vg,
                                         int jtile, unsigned short* KsBuf,
                                         unsigned short* VsBuf, int wv,
                                         int lane) {
  const unsigned short* kg = Kg + (size_t)jtile * 64 * HD;
  const unsigned short* vg = Vg + jtile * 64;
#pragma unroll
  for (int it = 0; it < 4; ++it) {
    // K: 4 rows x 256B per copy; lane -> row base+(l>>4), chunk l&15
    int kr = wv * 16 + it * 4 + (lane >> 4);
    async_copy16(kg + (size_t)kr * HD + (((lane & 15) ^ (kr & 7)) << 3),
                 KsBuf + (wv * 16 + it * 4) * 128);
    // V: 8 rows x 128B per copy; lane -> row base+(l>>3), chunk l&7
    int vr = wv * 32 + it * 8 + (lane >> 3);
    async_copy16(vg + (size_t)vr * S_LEN + (((lane & 7) ^ (vr & 7)) << 3),
                 VsBuf + (wv * 32 + it * 8) * 64);
  }
}

__global__ __launch_bounds__(256, 2) void flash_kernel(
    const unsigned short* __restrict__ Qb, const unsigned short* __restrict__ Kb,
    const unsigned short* __restrict__ Vt, unsigned short* __restrict__ attnb) {
  __shared__ __align__(16) unsigned short Ks[2][64 * 128];  // [krow][d] swz
  __shared__ __align__(16) unsigned short Vs[2][128 * 64];  // [d][kvpos] swz
  __shared__ __align__(16) unsigned short Ps[64 * 72];      // [qrow][kvpos]

  const int tid = threadIdx.x;
  const int bid = blockIdx.x;
  const int h = bid & 31;
  const int qt = 31 - (bid >> 5);  // heavy tiles dispatch first (LPT)
  const int g = h >> 2;
  const int wv = tid >> 6, lane = tid & 63;
  const int lrow = lane & 15, quad = lane >> 4;
  const float scale = 0.08838834764831845f;  // 1/sqrt(128)

  const unsigned short* Qg = Qb + ((size_t)h * S_LEN + qt * 64) * HD;
  bf16x8 qf[4];
#pragma unroll
  for (int ks = 0; ks < 4; ++ks)
    qf[ks] = *(const bf16x8*)(Qg + (size_t)(wv * 16 + lrow) * HD + ks * 32 +
                              quad * 8);

  // all-ones bf16 B-fragment for row-sum MFMA
  bf16x8 ones;
#pragma unroll
  for (int i = 0; i < 8; ++i) ones[i] = (short)0x3F80;

  const unsigned short* Kg = Kb + (size_t)g * S_LEN * HD;   // [s][d]
  const unsigned short* Vg = Vt + (size_t)g * HD * S_LEN;   // [d][s]

  f32x4 l_acc = {0.f, 0.f, 0.f, 0.f};
  f32x4 o_acc[8];
#pragma unroll
  for (int jc = 0; jc < 8; ++jc) {
    f32x4 z = {0.f, 0.f, 0.f, 0.f};
    o_acc[jc] = z;
  }

  // prologue: stage tile 0 into buffer 0
  stage_kv(Kg, Vg, 0, &Ks[0][0], &Vs[0][0], wv, lane);

  for (int jt = 0; jt <= qt; ++jt) {
    const int cb = jt & 1;
    // own copies of tile jt are the only outstanding VMEM ops
    asm volatile("s_waitcnt vmcnt(0)" ::: "memory");
    __builtin_amdgcn_s_barrier();  // all waves' copies landed; all waves
                                   // done reading buf cb from iter jt-2
    __builtin_amdgcn_sched_barrier(0);

    if (jt < qt)  // prefetch next tile; flies under this iter's compute
      stage_kv(Kg, Vg, jt + 1, &Ks[cb ^ 1][0], &Vs[cb ^ 1][0], wv, lane);

    // S = Q K^T (wave's 16 rows x 64 cols)
    f32x4 s_acc[4];
#pragma unroll
    for (int j = 0; j < 4; ++j) {
      f32x4 z = {0.f, 0.f, 0.f, 0.f};
      s_acc[j] = z;
    }
#pragma unroll
    for (int ks = 0; ks < 4; ++ks)
#pragma unroll
      for (int j = 0; j < 4; ++j) {
        int row = j * 16 + lrow;
        bf16x8 bk = *(const bf16x8*)&Ks[cb][row * 128 +
                                           (((ks * 4 + quad) ^ (row & 7)) << 3)];
        s_acc[j] = __builtin_amdgcn_mfma_f32_16x16x32_bf16(qf[ks], bk,
                                                           s_acc[j], 0, 0, 0);
      }

    // fixed-max softmax: p = exp(s*scale - 12); mask only on diagonal tile
    if (jt == qt) {
#pragma unroll
      for (int r = 0; r < 4; ++r) {
        int grow = qt * 64 + wv * 16 + quad * 4 + r;
#pragma unroll
        for (int j = 0; j < 4; ++j) {
          int gcol = jt * 64 + j * 16 + lrow;
          float p =
              (gcol <= grow) ? __expf(s_acc[j][r] * scale - 12.0f) : 0.f;
          Ps[(wv * 16 + quad * 4 + r) * 72 + j * 16 + lrow] = f2b(p);
        }
      }
    } else {
#pragma unroll
      for (int r = 0; r < 4; ++r)
#pragma unroll
        for (int j = 0; j < 4; ++j) {
          float p = __expf(s_acc[j][r] * scale - 12.0f);
          Ps[(wv * 16 + quad * 4 + r) * 72 + j * 16 + lrow] = f2b(p);
        }
    }
    // Ps band is wave-private: LDS drain only (must NOT drain vmcnt — the
    // next tile's global_load_lds copies are in flight)
    asm volatile("s_waitcnt lgkmcnt(0)" ::: "memory");
    __builtin_amdgcn_sched_barrier(0);

    // O += P V (16 rows x 128 cols, K=64); l += P * ones
#pragma unroll
    for (int kk = 0; kk < 2; ++kk) {
      bf16x8 ap =
          *(const bf16x8*)&Ps[(wv * 16 + lrow) * 72 + kk * 32 + 8 * quad];
      l_acc = __builtin_amdgcn_mfma_f32_16x16x32_bf16(ap, ones, l_acc, 0, 0, 0);
#pragma unroll
      for (int jc = 0; jc < 8; ++jc) {
        int row = jc * 16 + lrow;
        bf16x8 bv = *(const bf16x8*)&Vs[cb][row * 64 +
                                            (((kk * 4 + quad) ^ (row & 7)) << 3)];
        o_acc[jc] = __builtin_amdgcn_mfma_f32_16x16x32_bf16(ap, bv, o_acc[jc],
                                                            0, 0, 0);
      }
    }
    __builtin_amdgcn_s_barrier();  // all waves done reading buf cb before
                                   // iter jt+1 issues copies into buf cb
  }

  // epilogue: O / l -> attnb[s][h*128+d] (bf16)
#pragma unroll
  for (int r = 0; r < 4; ++r) {
    float inv_l = 1.0f / l_acc[r];
    int row = qt * 64 + wv * 16 + quad * 4 + r;
#pragma unroll
    for (int jc = 0; jc < 8; ++jc) {
      int col = jc * 16 + lrow;
      attnb[(size_t)row * MDIM + h * HD + col] = f2b(o_acc[jc][r] * inv_l);
    }
  }
}

// ---------------------------------------------------------------------------
extern "C" void kernel_launch(void* const* d_in, const int* in_sizes, int n_in,
                              void* d_out, int out_size, void* d_ws,
                              size_t ws_size, hipStream_t stream) {
  const float* x = (const float*)d_in[0];
  const float* Wqkv = (const float*)d_in[1];
  const float* bqkv = (const float*)d_in[2];
  const float* Wo = (const float*)d_in[3];
  const float* bo = (const float*)d_in[4];
  float* out = (float*)d_out;

  unsigned char* ws = (unsigned char*)d_ws;
  // region A [0, 50331648): phase1 = WT (6144x4096 bf16);
  //                         phase2 = WoT (33554432) + attnb (16777216)
  unsigned short* WT = (unsigned short*)ws;
  unsigned short* WoT = (unsigned short*)ws;
  unsigned short* attnb = (unsigned short*)(ws + 33554432);
  // region B: Q/K head-major bf16, V transposed [g][d][s]
  unsigned short* Qb = (unsigned short*)(ws + 50331648);  // 32*2048*128
  unsigned short* Kb = (unsigned short*)(ws + 67108864);  // 8*2048*128
  unsigned short* Vt = (unsigned short*)(ws + 71303168);  // 8*128*2048
  // d_out scratch: xb (bf16 x) in [0,16MB); RoPE table in [16MB,17MB).
  // Both consumed before gemm2 overwrites d_out with the final output.
  unsigned short* xb = (unsigned short*)d_out;
  float2* rtab = (float2*)((unsigned char*)d_out + 16777216);

  // 0. x f32 -> bf16 (into d_out scratch) + RoPE cos/sin table
  convert_x<<<(S_LEN * MDIM / 8) / 256, 256, 0, stream>>>(x, xb);
  rope_table<<<(S_LEN * 64) / 256, 256, 0, stream>>>(rtab);
  // 1. Wqkv [4096][6144] f32 -> WT [6144][4096] bf16
  transpose_convert<<<dim3(NFUSED / 64, MDIM / 64), 256, 0, stream>>>(
      Wqkv, WT, MDIM, NFUSED);
  // 2. QKV GEMM with fused bias + RoPE + head split (V transposed)
  gemm1_kernel<<<dim3(NFUSED / 256, S_LEN / 256), 512, 0, stream>>>(
      xb, WT, bqkv, rtab, Qb, Kb, Vt);
  // 3. Wo [4096][4096] f32 -> WoT [4096][4096] bf16 (reuses WT region)
  transpose_convert<<<dim3(MDIM / 64, MDIM / 64), 256, 0, stream>>>(Wo, WoT,
                                                                    MDIM, MDIM);
  // 4. causal GQA flash attention -> attnb bf16 (1D LPT grid)
  flash_kernel<<<S_LEN / 64 * NHEADS, 256, 0, stream>>>(Qb, Kb, Vt, attnb);
  // 5. output projection (overwrites xb scratch region of d_out)
  gemm2_kernel<<<dim3(MDIM / 256, S_LEN / 128), 512, 0, stream>>>(attnb, WoT,
                                                                  bo, out);
}

// Round 11
// 475.937 us; speedup vs baseline: 1.0411x; 1.0182x over previous
//
#include <hip/hip_runtime.h>
#include <hip/hip_bf16.h>
#include <math.h>

#define S_LEN  2048
#define MDIM   4096
#define NHEADS 32
#define NKV    8
#define HD     128
#define KVDIM  1024
#define NFUSED (MDIM + 2 * KVDIM) /* 6144 */

typedef short bf16x8 __attribute__((ext_vector_type(8)));
typedef float f32x4 __attribute__((ext_vector_type(4)));
typedef float f32x16 __attribute__((ext_vector_type(16)));

__device__ __forceinline__ unsigned short f2b(float f) {
  union { float f; unsigned int u; } v; v.f = f;
  unsigned int r = v.u + 0x7FFFu + ((v.u >> 16) & 1u);
  return (unsigned short)(r >> 16);
}
__device__ __forceinline__ float b2f(unsigned short h) {
  union { unsigned int u; float f; } v; v.u = ((unsigned int)h) << 16;
  return v.f;
}

// async global->LDS, 16B per lane; lds dest = wave-uniform base + lane*16
__device__ __forceinline__ void async_copy16(const void* g, void* l) {
  __builtin_amdgcn_global_load_lds(
      (const __attribute__((address_space(1))) unsigned int*)g,
      (__attribute__((address_space(3))) unsigned int*)l, 16, 0, 0);
}

// ---------------------------------------------------------------------------
// Fused prep kernel (round 10): convert_x + rope_table + transpose(Wqkv) in
// ONE launch. These three jobs are independent inputs of gemm1; fusing them
// removes 2 launch gaps and 2 ramp-down tails where the chip idles (7 serial
// launches previously; the small kernels each under-fill during drain).
// Block partition: [0,4096) convert_x, [4096,4608) rope, [4608,10752)
// transpose Wqkv (n-tile = t%96, k-tile = t/96 — matches old 2D grid).
// NOTE: transpose(Wo) CANNOT fuse here: WoT aliases the WT workspace region
// and must be written only after gemm1 consumed WT.
// ---------------------------------------------------------------------------
__global__ __launch_bounds__(256) void prep_kernel(
    const float* __restrict__ x, const float* __restrict__ Wqkv,
    unsigned short* __restrict__ xb, float2* __restrict__ rtab,
    unsigned short* __restrict__ WT) {
  __shared__ float t[64 * 65];  // used by the transpose branch only
  const int b = blockIdx.x;
  const int tid = threadIdx.x;

  if (b < 4096) {
    // ---- x f32 -> bf16 (one thread per 8 elements) ----
    size_t i = (size_t)b * 256 + tid;
    const float4 a = ((const float4*)x)[2 * i];
    const float4 c = ((const float4*)x)[2 * i + 1];
    unsigned short o[8] = {f2b(a.x), f2b(a.y), f2b(a.z), f2b(a.w),
                           f2b(c.x), f2b(c.y), f2b(c.z), f2b(c.w)};
    *(int4*)(xb + 8 * i) = *(const int4*)o;
  } else if (b < 4608) {
    // ---- RoPE table: rtab[s*64+d] = (cos,sin)(s * 50000^(-d/64)) ----
    int idx = (b - 4096) * 256 + tid;  // 0..131071
    int s = idx >> 6, d = idx & 63;
    float inv_freq = __expf(-0.16905903569f * (float)d);
    float ang = (float)s * inv_freq;
    rtab[idx] = make_float2(cosf(ang), sinf(ang));
  } else {
    // ---- transpose+convert Wqkv [4096][6144] f32 -> WT [6144][4096] bf16,
    //      64x64 tiles, coalesced loads, padded-f32 LDS staging ----
    const int tt = b - 4608;            // 0..6143
    const int n0 = (tt % 96) << 6;      // n tile
    const int k0 = (tt / 96) << 6;      // k tile
    const int K = MDIM, N = NFUSED;
#pragma unroll
    for (int it = 0; it < 4; ++it) {
      int idx = it * 256 + tid;        // 0..1023
      int r = idx >> 4;                // k row 0..63
      int cq = idx & 15;               // float4 col group
      const float4 v =
          *(const float4*)(Wqkv + (size_t)(k0 + r) * N + n0 + (cq << 2));
      t[r * 65 + (cq << 2) + 0] = v.x;
      t[r * 65 + (cq << 2) + 1] = v.y;
      t[r * 65 + (cq << 2) + 2] = v.z;
      t[r * 65 + (cq << 2) + 3] = v.w;
    }
    __syncthreads();
    const int n = tid >> 2, kk = (tid & 3) << 4;
    unsigned short o[16];
#pragma unroll
    for (int j = 0; j < 16; ++j) o[j] = f2b(t[(kk + j) * 65 + n]);
    *(int4*)(WT + (size_t)(n0 + n) * K + k0 + kk) = *(const int4*)&o[0];
    *(int4*)(WT + (size_t)(n0 + n) * K + k0 + kk + 8) = *(const int4*)&o[8];
  }
}

// ---------------------------------------------------------------------------
// Transpose + convert: W [K][N] f32 -> WT [N][K] bf16. 64x64 tiles.
// (standalone copy for Wo — must run after gemm1, see prep_kernel note)
// ---------------------------------------------------------------------------
__global__ __launch_bounds__(256) void transpose_convert(
    const float* __restrict__ W, unsigned short* __restrict__ WT, int K,
    int N) {
  __shared__ float t[64 * 65];  // [k][n], pad 64->65 (f32)
  const int k0 = blockIdx.y << 6, n0 = blockIdx.x << 6;
  const int tid = threadIdx.x;
#pragma unroll
  for (int it = 0; it < 4; ++it) {
    int idx = it * 256 + tid;        // 0..1023
    int r = idx >> 4;                // k row 0..63
    int cq = idx & 15;               // float4 col group
    const float4 v =
        *(const float4*)(W + (size_t)(k0 + r) * N + n0 + (cq << 2));
    t[r * 65 + (cq << 2) + 0] = v.x;
    t[r * 65 + (cq << 2) + 1] = v.y;
    t[r * 65 + (cq << 2) + 2] = v.z;
    t[r * 65 + (cq << 2) + 3] = v.w;
  }
  __syncthreads();
  const int n = tid >> 2, kk = (tid & 3) << 4;
  unsigned short o[16];
#pragma unroll
  for (int j = 0; j < 16; ++j) o[j] = f2b(t[(kk + j) * 65 + n]);
  *(int4*)(WT + (size_t)(n0 + n) * K + k0 + kk) = *(const int4*)&o[0];
  *(int4*)(WT + (size_t)(n0 + n) * K + k0 + kk + 8) = *(const int4*)&o[8];
}

// ---------------------------------------------------------------------------
// GEMM1: fused = xb[2048][4096](bf16) * WT^T + bqkv, RoPE + head-split
// epilogue. 256x256 tile, BK=64, 8 waves (2M x 4N), dbuf 128KiB LDS,
// 32x32x16 MFMA, single vmcnt(0)+barrier per K-tile. (round-7 version,
// best measured: 124.5us; r8's 128² geometry regressed; FROZEN.)
//
// Hash swizzle: hash(row) = (row ^ (row>>3)) & 7 (fixes the 4-way conflict
// the 32x32 fragment pattern had with row&7; verified 9.67M -> 229K).
// Write: dest row = c*64+wave*8+lr8 -> hash = lr8^wave; source chunk =
// lc8^lr8^wave (constant across c). Read: row = woff + l31 + i*32 -> hash
// = base ^ (i&1?4:0), base = (l31&7)^(l31>>3); even/odd i use co / co^32.
// C/D: col=lane&31, row=(reg&3)+8*(reg>>2)+4*(lane>>5) [m74/m101].
// acc = f32x16[4][2], statically indexed (rule #20).
// ---------------------------------------------------------------------------
__global__ __launch_bounds__(512, 2) void gemm1_kernel(
    const unsigned short* __restrict__ xb,
    const unsigned short* __restrict__ WT, const float* __restrict__ bias,
    const float2* __restrict__ rtab, unsigned short* __restrict__ Qb,
    unsigned short* __restrict__ Kb, unsigned short* __restrict__ Vt) {
  // [slot][ A 256x64 | B 256x64 ] bf16 = 2 x 64KiB = 128KiB
  __shared__ unsigned short sm[2][32768];

  const int tid = threadIdx.x;
  const int bn = blockIdx.x, bm = blockIdx.y;
  const int lane = tid & 63, wave = tid >> 6;
  const int l31 = lane & 31, lh = lane >> 5;
  const int wrow = wave >> 2, wcol = wave & 3;  // 2M x 4N wave grid

  f32x16 acc[4][2];
#pragma unroll
  for (int i = 0; i < 4; ++i)
#pragma unroll
    for (int j = 0; j < 2; ++j)
#pragma unroll
      for (int r = 0; r < 16; ++r) acc[i][j][r] = 0.f;

  // staging: each copy = 64 rows over 8 waves (8 rows/wave); lane ->
  // (row lr8, phys chunk lc8). hash(destrow)=lr8^wave -> src chunk below.
  const int lr8 = lane >> 3, lc8 = lane & 7;
  const int baser = wave * 8 + lr8;                    // tile row (+c*64)
  const size_t swz = (size_t)((lc8 ^ lr8 ^ wave) << 3);  // pre-swizzle
  const unsigned short* sA = xb + (size_t)(bm * 256 + baser) * MDIM + swz;
  const unsigned short* sB = WT + (size_t)(bn * 256 + baser) * MDIM + swz;

  auto stage = [&](int slot, int k0) {
#pragma unroll
    for (int c = 0; c < 4; ++c) {
      unsigned short* dA = &sm[slot][(c * 64 + wave * 8) * 64];
      unsigned short* dB = &sm[slot][16384 + (c * 64 + wave * 8) * 64];
      async_copy16(sA + (size_t)c * 64 * MDIM + k0, dA);
      async_copy16(sB + (size_t)c * 64 * MDIM + k0, dB);
    }
  };

  // fragment-read invariants
  const int arow0 = wrow * 128 + l31;  // + i*32
  const int brow0 = wcol * 64 + l31;   // + jj*32
  const int base = (l31 & 7) ^ (l31 >> 3);

  stage(0, 0);  // prologue: K-tile 0 -> slot 0

  for (int kt = 0; kt < 64; ++kt) {
    const int p = kt & 1;
    // own 8 copies of tile kt are the only outstanding VMEM ops; each wave
    // drains ITS copies before the barrier => after barrier all landed.
    asm volatile("s_waitcnt vmcnt(0)" ::: "memory");
    __builtin_amdgcn_s_barrier();  // also: all waves done reading slot p^1
    __builtin_amdgcn_sched_barrier(0);

    if (kt < 63) stage(p ^ 1, (kt + 1) << 6);  // flies under this compute

    const unsigned short* Asl = &sm[p][0];
    const unsigned short* Bsl = &sm[p][16384];
    __builtin_amdgcn_s_setprio(1);
#pragma unroll
    for (int t = 0; t < 4; ++t) {  // k-step of 16
      const int coE = (((2 * t + lh) ^ base) << 3);  // even i/jj rows
      const int coO = coE ^ 32;                      // odd  i/jj rows (+4 hash)
      bf16x8 bfr[2], af[4];
      bfr[0] = *(const bf16x8*)&Bsl[(brow0) * 64 + coE];
      bfr[1] = *(const bf16x8*)&Bsl[(brow0 + 32) * 64 + coO];
      af[0] = *(const bf16x8*)&Asl[(arow0) * 64 + coE];
      af[1] = *(const bf16x8*)&Asl[(arow0 + 32) * 64 + coO];
      af[2] = *(const bf16x8*)&Asl[(arow0 + 64) * 64 + coE];
      af[3] = *(const bf16x8*)&Asl[(arow0 + 96) * 64 + coO];
#pragma unroll
      for (int i = 0; i < 4; ++i)
#pragma unroll
        for (int jj = 0; jj < 2; ++jj)
          acc[i][jj] = __builtin_amdgcn_mfma_f32_32x32x16_bf16(
              af[i], bfr[jj], acc[i][jj], 0, 0, 0);
    }
    __builtin_amdgcn_s_setprio(0);
  }
  __syncthreads();  // K-loop reads done before Ct overwrites staging LDS

  // ---- epilogue: two 128-col halves; Ct[256][132] reuses staging LDS ----
  unsigned short* Ct = &sm[0][0];
#pragma unroll 1
  for (int h = 0; h < 2; ++h) {
    const int slot = 2 * bn + h;  // 0..31 Q, 32..39 K, 40..47 V
    if ((wcol >> 1) == h) {       // waves owning this col half write acc
#pragma unroll
      for (int i = 0; i < 4; ++i)
#pragma unroll
        for (int jj = 0; jj < 2; ++jj) {
          int lc = (wcol & 1) * 64 + jj * 32 + l31;
          float bv = bias[slot * 128 + lc];
#pragma unroll
          for (int r = 0; r < 16; ++r) {
            int lrw = wrow * 128 + i * 32 + (r & 3) + 8 * (r >> 2) + 4 * lh;
            Ct[lrw * 132 + lc] = f2b(acc[i][jj][r] + bv);
          }
        }
    }
    __syncthreads();

    if (slot < 40) {
#pragma unroll 4
      for (int it = 0; it < 32; ++it) {
        int row = it * 8 + wave;  // 0..255
        int d = lane;
        float x1 = b2f(Ct[row * 132 + d]);
        float x2 = b2f(Ct[row * 132 + d + 64]);
        int s = bm * 256 + row;
        float2 cs = rtab[s * 64 + d];  // (cos, sin) precomputed
        float o1 = x1 * cs.x - x2 * cs.y;
        float o2 = x2 * cs.x + x1 * cs.y;
        unsigned short* dst;
        if (slot < 32)
          dst = Qb + ((size_t)slot * S_LEN + s) * HD;
        else
          dst = Kb + ((size_t)(slot - 32) * S_LEN + s) * HD;
        dst[d] = f2b(o1);
        dst[d + 64] = f2b(o2);
      }
    } else {
      // V: write transposed Vt[g][d][s], coalesced along s
      const int g = slot - 40;
      unsigned short* Vtg = Vt + (size_t)g * HD * S_LEN;  // [128][2048]
      const int dp = tid >> 3;         // d-pair 0..63
      const int sq = (tid & 7) << 5;   // s-eighth 0,32,..,224
      unsigned short buf0[32], buf1[32];
#pragma unroll
      for (int i = 0; i < 32; ++i) {
        unsigned int w = *(const unsigned int*)&Ct[(sq + i) * 132 + 2 * dp];
        buf0[i] = (unsigned short)(w & 0xffffu);
        buf1[i] = (unsigned short)(w >> 16);
      }
      const int s0 = bm * 256 + sq;
#pragma unroll
      for (int c = 0; c < 2; ++c) {
        unsigned short* dst = Vtg + (size_t)(2 * dp + c) * S_LEN + s0;
        const unsigned short* b = c ? buf1 : buf0;
#pragma unroll
        for (int q4 = 0; q4 < 4; ++q4)
          *(int4*)(dst + q4 * 8) = *(const int4*)(b + q4 * 8);
      }
    }
    __syncthreads();  // pass-h reads done before pass h+1 overwrites Ct
  }
}

// ---------------------------------------------------------------------------
// GEMM2: out = attnb[2048][4096](bf16) * WoT^T + bo (f32 out).
// BM=128 x BN=256 (grid 16x16 = 256 blocks = 1/CU), BK=64, 8 waves (2M x 4N,
// 64x64 per wave), dbuf 96KiB LDS, 32x32x16 MFMA, single barrier per K-tile.
// Generalized hash swizzle (r7). FROZEN.
// ---------------------------------------------------------------------------
__global__ __launch_bounds__(512, 2) void gemm2_kernel(
    const unsigned short* __restrict__ Ab16,
    const unsigned short* __restrict__ BT, const float* __restrict__ bias,
    float* __restrict__ C) {
  // [slot][ A 128x64 | B 256x64 ] bf16 = 2 x 48KiB = 96KiB
  __shared__ unsigned short sm[2][24576];

  const int tid = threadIdx.x;
  const int bn = blockIdx.x, bm = blockIdx.y;  // bn: N/256, bm: M/128
  const int lane = tid & 63, wave = tid >> 6;
  const int l31 = lane & 31, lh = lane >> 5;
  const int wrow = wave >> 2, wcol = wave & 3;  // 2M x 4N wave grid

  f32x16 acc[2][2];
#pragma unroll
  for (int i = 0; i < 2; ++i)
#pragma unroll
    for (int j = 0; j < 2; ++j)
#pragma unroll
      for (int r = 0; r < 16; ++r) acc[i][j][r] = 0.f;

  const int lr8 = lane >> 3, lc8 = lane & 7;
  const int baser = wave * 8 + lr8;
  const size_t swz = (size_t)((lc8 ^ lr8 ^ wave) << 3);
  const unsigned short* sA = Ab16 + (size_t)(bm * 128 + baser) * MDIM + swz;
  const unsigned short* sB = BT + (size_t)(bn * 256 + baser) * MDIM + swz;

  auto stage = [&](int slot, int k0) {
#pragma unroll
    for (int c = 0; c < 2; ++c)
      async_copy16(sA + (size_t)c * 64 * MDIM + k0,
                   &sm[slot][(c * 64 + wave * 8) * 64]);
#pragma unroll
    for (int c = 0; c < 4; ++c)
      async_copy16(sB + (size_t)c * 64 * MDIM + k0,
                   &sm[slot][8192 + (c * 64 + wave * 8) * 64]);
  };

  const int arow0 = wrow * 64 + l31;  // + i*32
  const int brow0 = wcol * 64 + l31;  // + jj*32
  const int base = (l31 & 7) ^ (l31 >> 3);

  stage(0, 0);  // prologue: K-tile 0 -> slot 0

#pragma unroll 1
  for (int kt = 0; kt < 64; ++kt) {
    const int p = kt & 1;
    asm volatile("s_waitcnt vmcnt(0)" ::: "memory");
    __builtin_amdgcn_s_barrier();
    __builtin_amdgcn_sched_barrier(0);

    if (kt < 63) stage(p ^ 1, (kt + 1) << 6);

    const unsigned short* Asl = &sm[p][0];
    const unsigned short* Bsl = &sm[p][8192];
    __builtin_amdgcn_s_setprio(1);
#pragma unroll
    for (int t = 0; t < 4; ++t) {
      const int coE = (((2 * t + lh) ^ base) << 3);
      const int coO = coE ^ 32;
      bf16x8 bfr[2], af[2];
      bfr[0] = *(const bf16x8*)&Bsl[(brow0) * 64 + coE];
      bfr[1] = *(const bf16x8*)&Bsl[(brow0 + 32) * 64 + coO];
      af[0] = *(const bf16x8*)&Asl[(arow0) * 64 + coE];
      af[1] = *(const bf16x8*)&Asl[(arow0 + 32) * 64 + coO];
#pragma unroll
      for (int i = 0; i < 2; ++i)
#pragma unroll
        for (int jj = 0; jj < 2; ++jj)
          acc[i][jj] = __builtin_amdgcn_mfma_f32_32x32x16_bf16(
              af[i], bfr[jj], acc[i][jj], 0, 0, 0);
    }
    __builtin_amdgcn_s_setprio(0);
  }

  // epilogue: direct f32 store with bias
#pragma unroll
  for (int i = 0; i < 2; ++i)
#pragma unroll
    for (int jj = 0; jj < 2; ++jj) {
      int gcol = bn * 256 + wcol * 64 + jj * 32 + l31;
      float bv = bias[gcol];
#pragma unroll
      for (int r = 0; r < 16; ++r) {
        int grow =
            bm * 128 + wrow * 64 + i * 32 + (r & 3) + 8 * (r >> 2) + 4 * lh;
        C[(size_t)grow * MDIM + gcol] = acc[i][jj][r] + bv;
      }
    }
}

// ---------------------------------------------------------------------------
// Flash attention, causal, GQA. Fixed-max softmax (scores bounded; exp(s-12)
// cannot overflow, o/l unchanged). Q in registers. K/V double-buffered LDS
// via global_load_lds with XOR-swizzled layout (pre-swizzled global source,
// linear LDS dest). One vmcnt(0)+barrier per KV-tile; prefetch issued after
// the barrier flies under the whole compute phase. Ps fence: lgkmcnt only.
// Row-sums via ones-MFMA. 1D LPT grid.
//
// Round 10: __launch_bounds__(256,3) — 3 blocks/CU (LDS 45KB x3 = 135 <=
// 160KB). The (256,2) bound was a leftover from the r0 register-prefetch
// kernel (which spilled at 3); this kernel is at 72 VGPR, and 3 waves/SIMD
// needs only <=168. +50% resident waves to overlap the per-tile
// vmcnt-drain/barrier convoy across blocks.
// ---------------------------------------------------------------------------
__device__ __forceinline__ void stage_kv(const unsigned short* __restrict__ Kg,
                                         const unsigned short* __restrict__ Vg,
                                         int jtile, unsigned short* KsBuf,
                                         unsigned short* VsBuf, int wv,
                                         int lane) {
  const unsigned short* kg = Kg + (size_t)jtile * 64 * HD;
  const unsigned short* vg = Vg + jtile * 64;
#pragma unroll
  for (int it = 0; it < 4; ++it) {
    // K: 4 rows x 256B per copy; lane -> row base+(l>>4), chunk l&15
    int kr = wv * 16 + it * 4 + (lane >> 4);
    async_copy16(kg + (size_t)kr * HD + (((lane & 15) ^ (kr & 7)) << 3),
                 KsBuf + (wv * 16 + it * 4) * 128);
    // V: 8 rows x 128B per copy; lane -> row base+(l>>3), chunk l&7
    int vr = wv * 32 + it * 8 + (lane >> 3);
    async_copy16(vg + (size_t)vr * S_LEN + (((lane & 7) ^ (vr & 7)) << 3),
                 VsBuf + (wv * 32 + it * 8) * 64);
  }
}

__global__ __launch_bounds__(256, 3) void flash_kernel(
    const unsigned short* __restrict__ Qb, const unsigned short* __restrict__ Kb,
    const unsigned short* __restrict__ Vt, unsigned short* __restrict__ attnb) {
  __shared__ __align__(16) unsigned short Ks[2][64 * 128];  // [krow][d] swz
  __shared__ __align__(16) unsigned short Vs[2][128 * 64];  // [d][kvpos] swz
  __shared__ __align__(16) unsigned short Ps[64 * 72];      // [qrow][kvpos]

  const int tid = threadIdx.x;
  const int bid = blockIdx.x;
  const int h = bid & 31;
  const int qt = 31 - (bid >> 5);  // heavy tiles dispatch first (LPT)
  const int g = h >> 2;
  const int wv = tid >> 6, lane = tid & 63;
  const int lrow = lane & 15, quad = lane >> 4;
  const float scale = 0.08838834764831845f;  // 1/sqrt(128)

  const unsigned short* Qg = Qb + ((size_t)h * S_LEN + qt * 64) * HD;
  bf16x8 qf[4];
#pragma unroll
  for (int ks = 0; ks < 4; ++ks)
    qf[ks] = *(const bf16x8*)(Qg + (size_t)(wv * 16 + lrow) * HD + ks * 32 +
                              quad * 8);

  // all-ones bf16 B-fragment for row-sum MFMA
  bf16x8 ones;
#pragma unroll
  for (int i = 0; i < 8; ++i) ones[i] = (short)0x3F80;

  const unsigned short* Kg = Kb + (size_t)g * S_LEN * HD;   // [s][d]
  const unsigned short* Vg = Vt + (size_t)g * HD * S_LEN;   // [d][s]

  f32x4 l_acc = {0.f, 0.f, 0.f, 0.f};
  f32x4 o_acc[8];
#pragma unroll
  for (int jc = 0; jc < 8; ++jc) {
    f32x4 z = {0.f, 0.f, 0.f, 0.f};
    o_acc[jc] = z;
  }

  // prologue: stage tile 0 into buffer 0
  stage_kv(Kg, Vg, 0, &Ks[0][0], &Vs[0][0], wv, lane);

  for (int jt = 0; jt <= qt; ++jt) {
    const int cb = jt & 1;
    // own copies of tile jt are the only outstanding VMEM ops
    asm volatile("s_waitcnt vmcnt(0)" ::: "memory");
    __builtin_amdgcn_s_barrier();  // all waves' copies landed; all waves
                                   // done reading buf cb from iter jt-2
    __builtin_amdgcn_sched_barrier(0);

    if (jt < qt)  // prefetch next tile; flies under this iter's compute
      stage_kv(Kg, Vg, jt + 1, &Ks[cb ^ 1][0], &Vs[cb ^ 1][0], wv, lane);

    // S = Q K^T (wave's 16 rows x 64 cols)
    f32x4 s_acc[4];
#pragma unroll
    for (int j = 0; j < 4; ++j) {
      f32x4 z = {0.f, 0.f, 0.f, 0.f};
      s_acc[j] = z;
    }
#pragma unroll
    for (int ks = 0; ks < 4; ++ks)
#pragma unroll
      for (int j = 0; j < 4; ++j) {
        int row = j * 16 + lrow;
        bf16x8 bk = *(const bf16x8*)&Ks[cb][row * 128 +
                                           (((ks * 4 + quad) ^ (row & 7)) << 3)];
        s_acc[j] = __builtin_amdgcn_mfma_f32_16x16x32_bf16(qf[ks], bk,
                                                           s_acc[j], 0, 0, 0);
      }

    // fixed-max softmax: p = exp(s*scale - 12); mask only on diagonal tile
    if (jt == qt) {
#pragma unroll
      for (int r = 0; r < 4; ++r) {
        int grow = qt * 64 + wv * 16 + quad * 4 + r;
#pragma unroll
        for (int j = 0; j < 4; ++j) {
          int gcol = jt * 64 + j * 16 + lrow;
          float p =
              (gcol <= grow) ? __expf(s_acc[j][r] * scale - 12.0f) : 0.f;
          Ps[(wv * 16 + quad * 4 + r) * 72 + j * 16 + lrow] = f2b(p);
        }
      }
    } else {
#pragma unroll
      for (int r = 0; r < 4; ++r)
#pragma unroll
        for (int j = 0; j < 4; ++j) {
          float p = __expf(s_acc[j][r] * scale - 12.0f);
          Ps[(wv * 16 + quad * 4 + r) * 72 + j * 16 + lrow] = f2b(p);
        }
    }
    // Ps band is wave-private: LDS drain only (must NOT drain vmcnt — the
    // next tile's global_load_lds copies are in flight)
    asm volatile("s_waitcnt lgkmcnt(0)" ::: "memory");
    __builtin_amdgcn_sched_barrier(0);

    // O += P V (16 rows x 128 cols, K=64); l += P * ones
#pragma unroll
    for (int kk = 0; kk < 2; ++kk) {
      bf16x8 ap =
          *(const bf16x8*)&Ps[(wv * 16 + lrow) * 72 + kk * 32 + 8 * quad];
      l_acc = __builtin_amdgcn_mfma_f32_16x16x32_bf16(ap, ones, l_acc, 0, 0, 0);
#pragma unroll
      for (int jc = 0; jc < 8; ++jc) {
        int row = jc * 16 + lrow;
        bf16x8 bv = *(const bf16x8*)&Vs[cb][row * 64 +
                                            (((kk * 4 + quad) ^ (row & 7)) << 3)];
        o_acc[jc] = __builtin_amdgcn_mfma_f32_16x16x32_bf16(ap, bv, o_acc[jc],
                                                            0, 0, 0);
      }
    }
    __builtin_amdgcn_s_barrier();  // all waves done reading buf cb before
                                   // iter jt+1 issues copies into buf cb
  }

  // epilogue: O / l -> attnb[s][h*128+d] (bf16)
#pragma unroll
  for (int r = 0; r < 4; ++r) {
    float inv_l = 1.0f / l_acc[r];
    int row = qt * 64 + wv * 16 + quad * 4 + r;
#pragma unroll
    for (int jc = 0; jc < 8; ++jc) {
      int col = jc * 16 + lrow;
      attnb[(size_t)row * MDIM + h * HD + col] = f2b(o_acc[jc][r] * inv_l);
    }
  }
}

// ---------------------------------------------------------------------------
extern "C" void kernel_launch(void* const* d_in, const int* in_sizes, int n_in,
                              void* d_out, int out_size, void* d_ws,
                              size_t ws_size, hipStream_t stream) {
  const float* x = (const float*)d_in[0];
  const float* Wqkv = (const float*)d_in[1];
  const float* bqkv = (const float*)d_in[2];
  const float* Wo = (const float*)d_in[3];
  const float* bo = (const float*)d_in[4];
  float* out = (float*)d_out;

  unsigned char* ws = (unsigned char*)d_ws;
  // region A [0, 50331648): phase1 = WT (6144x4096 bf16);
  //                         phase2 = WoT (33554432) + attnb (16777216)
  unsigned short* WT = (unsigned short*)ws;
  unsigned short* WoT = (unsigned short*)ws;
  unsigned short* attnb = (unsigned short*)(ws + 33554432);
  // region B: Q/K head-major bf16, V transposed [g][d][s]
  unsigned short* Qb = (unsigned short*)(ws + 50331648);  // 32*2048*128
  unsigned short* Kb = (unsigned short*)(ws + 67108864);  // 8*2048*128
  unsigned short* Vt = (unsigned short*)(ws + 71303168);  // 8*128*2048
  // d_out scratch: xb (bf16 x) in [0,16MB); RoPE table in [16MB,17MB).
  // Both consumed before gemm2 overwrites d_out with the final output.
  unsigned short* xb = (unsigned short*)d_out;
  float2* rtab = (float2*)((unsigned char*)d_out + 16777216);

  // 0. fused prep: convert_x + rope table + transpose(Wqkv) -> WT
  prep_kernel<<<4096 + 512 + 6144, 256, 0, stream>>>(x, Wqkv, xb, rtab, WT);
  // 1. QKV GEMM with fused bias + RoPE + head split (V transposed)
  gemm1_kernel<<<dim3(NFUSED / 256, S_LEN / 256), 512, 0, stream>>>(
      xb, WT, bqkv, rtab, Qb, Kb, Vt);
  // 2. Wo [4096][4096] f32 -> WoT [4096][4096] bf16 (reuses WT region —
  //    must run after gemm1 consumed WT)
  transpose_convert<<<dim3(MDIM / 64, MDIM / 64), 256, 0, stream>>>(Wo, WoT,
                                                                    MDIM, MDIM);
  // 3. causal GQA flash attention -> attnb bf16 (1D LPT grid)
  flash_kernel<<<S_LEN / 64 * NHEADS, 256, 0, stream>>>(Qb, Kb, Vt, attnb);
  // 4. output projection (overwrites xb scratch region of d_out)
  gemm2_kernel<<<dim3(MDIM / 256, S_LEN / 128), 512, 0, stream>>>(attnb, WoT,
                                                                  bo, out);
}

// Round 12
// 457.982 us; speedup vs baseline: 1.0819x; 1.0392x over previous
//
#include <hip/hip_runtime.h>
#include <hip/hip_bf16.h>
#include <math.h>

#define S_LEN  2048
#define MDIM   4096
#define NHEADS 32
#define NKV    8
#define HD     128
#define KVDIM  1024
#define NFUSED (MDIM + 2 * KVDIM) /* 6144 */

typedef short bf16x8 __attribute__((ext_vector_type(8)));
typedef float f32x4 __attribute__((ext_vector_type(4)));
typedef float f32x16 __attribute__((ext_vector_type(16)));

__device__ __forceinline__ unsigned short f2b(float f) {
  union { float f; unsigned int u; } v; v.f = f;
  unsigned int r = v.u + 0x7FFFu + ((v.u >> 16) & 1u);
  return (unsigned short)(r >> 16);
}
__device__ __forceinline__ float b2f(unsigned short h) {
  union { unsigned int u; float f; } v; v.u = ((unsigned int)h) << 16;
  return v.f;
}

// async global->LDS, 16B per lane; lds dest = wave-uniform base + lane*16
__device__ __forceinline__ void async_copy16(const void* g, void* l) {
  __builtin_amdgcn_global_load_lds(
      (const __attribute__((address_space(1))) unsigned int*)g,
      (__attribute__((address_space(3))) unsigned int*)l, 16, 0, 0);
}

// ---------------------------------------------------------------------------
// Fused prep kernel: convert_x + rope_table + transpose(Wqkv) in ONE launch.
// Block partition: [0,4096) convert_x, [4096,4608) rope, [4608,10752)
// transpose Wqkv (n-tile = t%96, k-tile = t/96).
// NOTE: transpose(Wo) cannot fuse here: WoT aliases the WT workspace region
// and must be written only after gemm1 consumed WT. It is fused into the
// flash launch instead (round 11).
// ---------------------------------------------------------------------------
__global__ __launch_bounds__(256) void prep_kernel(
    const float* __restrict__ x, const float* __restrict__ Wqkv,
    unsigned short* __restrict__ xb, float2* __restrict__ rtab,
    unsigned short* __restrict__ WT) {
  __shared__ float t[64 * 65];  // used by the transpose branch only
  const int b = blockIdx.x;
  const int tid = threadIdx.x;

  if (b < 4096) {
    // ---- x f32 -> bf16 (one thread per 8 elements) ----
    size_t i = (size_t)b * 256 + tid;
    const float4 a = ((const float4*)x)[2 * i];
    const float4 c = ((const float4*)x)[2 * i + 1];
    unsigned short o[8] = {f2b(a.x), f2b(a.y), f2b(a.z), f2b(a.w),
                           f2b(c.x), f2b(c.y), f2b(c.z), f2b(c.w)};
    *(int4*)(xb + 8 * i) = *(const int4*)o;
  } else if (b < 4608) {
    // ---- RoPE table: rtab[s*64+d] = (cos,sin)(s * 50000^(-d/64)) ----
    int idx = (b - 4096) * 256 + tid;  // 0..131071
    int s = idx >> 6, d = idx & 63;
    float inv_freq = __expf(-0.16905903569f * (float)d);
    float ang = (float)s * inv_freq;
    rtab[idx] = make_float2(cosf(ang), sinf(ang));
  } else {
    // ---- transpose+convert Wqkv [4096][6144] f32 -> WT [6144][4096] bf16,
    //      64x64 tiles, coalesced loads, padded-f32 LDS staging ----
    const int tt = b - 4608;            // 0..6143
    const int n0 = (tt % 96) << 6;      // n tile
    const int k0 = (tt / 96) << 6;      // k tile
    const int K = MDIM, N = NFUSED;
#pragma unroll
    for (int it = 0; it < 4; ++it) {
      int idx = it * 256 + tid;        // 0..1023
      int r = idx >> 4;                // k row 0..63
      int cq = idx & 15;               // float4 col group
      const float4 v =
          *(const float4*)(Wqkv + (size_t)(k0 + r) * N + n0 + (cq << 2));
      t[r * 65 + (cq << 2) + 0] = v.x;
      t[r * 65 + (cq << 2) + 1] = v.y;
      t[r * 65 + (cq << 2) + 2] = v.z;
      t[r * 65 + (cq << 2) + 3] = v.w;
    }
    __syncthreads();
    const int n = tid >> 2, kk = (tid & 3) << 4;
    unsigned short o[16];
#pragma unroll
    for (int j = 0; j < 16; ++j) o[j] = f2b(t[(kk + j) * 65 + n]);
    *(int4*)(WT + (size_t)(n0 + n) * K + k0 + kk) = *(const int4*)&o[0];
    *(int4*)(WT + (size_t)(n0 + n) * K + k0 + kk + 8) = *(const int4*)&o[8];
  }
}

// ---------------------------------------------------------------------------
// GEMM1: fused = xb[2048][4096](bf16) * WT^T + bqkv, RoPE + head-split
// epilogue. 256x256 tile, BK=64, 8 waves (2M x 4N), dbuf 128KiB LDS,
// 32x32x16 MFMA, single vmcnt(0)+barrier per K-tile. (round-7 version,
// best measured: 122-125us; FROZEN.)
//
// Hash swizzle: hash(row) = (row ^ (row>>3)) & 7 (fixes the 4-way conflict
// the 32x32 fragment pattern had with row&7; verified 9.67M -> 229K).
// Write: dest row = c*64+wave*8+lr8 -> hash = lr8^wave; source chunk =
// lc8^lr8^wave (constant across c). Read: row = woff + l31 + i*32 -> hash
// = base ^ (i&1?4:0), base = (l31&7)^(l31>>3); even/odd i use co / co^32.
// C/D: col=lane&31, row=(reg&3)+8*(reg>>2)+4*(lane>>5) [m74/m101].
// acc = f32x16[4][2], statically indexed (rule #20).
// ---------------------------------------------------------------------------
__global__ __launch_bounds__(512, 2) void gemm1_kernel(
    const unsigned short* __restrict__ xb,
    const unsigned short* __restrict__ WT, const float* __restrict__ bias,
    const float2* __restrict__ rtab, unsigned short* __restrict__ Qb,
    unsigned short* __restrict__ Kb, unsigned short* __restrict__ Vt) {
  // [slot][ A 256x64 | B 256x64 ] bf16 = 2 x 64KiB = 128KiB
  __shared__ unsigned short sm[2][32768];

  const int tid = threadIdx.x;
  const int bn = blockIdx.x, bm = blockIdx.y;
  const int lane = tid & 63, wave = tid >> 6;
  const int l31 = lane & 31, lh = lane >> 5;
  const int wrow = wave >> 2, wcol = wave & 3;  // 2M x 4N wave grid

  f32x16 acc[4][2];
#pragma unroll
  for (int i = 0; i < 4; ++i)
#pragma unroll
    for (int j = 0; j < 2; ++j)
#pragma unroll
      for (int r = 0; r < 16; ++r) acc[i][j][r] = 0.f;

  // staging: each copy = 64 rows over 8 waves (8 rows/wave); lane ->
  // (row lr8, phys chunk lc8). hash(destrow)=lr8^wave -> src chunk below.
  const int lr8 = lane >> 3, lc8 = lane & 7;
  const int baser = wave * 8 + lr8;                    // tile row (+c*64)
  const size_t swz = (size_t)((lc8 ^ lr8 ^ wave) << 3);  // pre-swizzle
  const unsigned short* sA = xb + (size_t)(bm * 256 + baser) * MDIM + swz;
  const unsigned short* sB = WT + (size_t)(bn * 256 + baser) * MDIM + swz;

  auto stage = [&](int slot, int k0) {
#pragma unroll
    for (int c = 0; c < 4; ++c) {
      unsigned short* dA = &sm[slot][(c * 64 + wave * 8) * 64];
      unsigned short* dB = &sm[slot][16384 + (c * 64 + wave * 8) * 64];
      async_copy16(sA + (size_t)c * 64 * MDIM + k0, dA);
      async_copy16(sB + (size_t)c * 64 * MDIM + k0, dB);
    }
  };

  // fragment-read invariants
  const int arow0 = wrow * 128 + l31;  // + i*32
  const int brow0 = wcol * 64 + l31;   // + jj*32
  const int base = (l31 & 7) ^ (l31 >> 3);

  stage(0, 0);  // prologue: K-tile 0 -> slot 0

  for (int kt = 0; kt < 64; ++kt) {
    const int p = kt & 1;
    // own 8 copies of tile kt are the only outstanding VMEM ops; each wave
    // drains ITS copies before the barrier => after barrier all landed.
    asm volatile("s_waitcnt vmcnt(0)" ::: "memory");
    __builtin_amdgcn_s_barrier();  // also: all waves done reading slot p^1
    __builtin_amdgcn_sched_barrier(0);

    if (kt < 63) stage(p ^ 1, (kt + 1) << 6);  // flies under this compute

    const unsigned short* Asl = &sm[p][0];
    const unsigned short* Bsl = &sm[p][16384];
    __builtin_amdgcn_s_setprio(1);
#pragma unroll
    for (int t = 0; t < 4; ++t) {  // k-step of 16
      const int coE = (((2 * t + lh) ^ base) << 3);  // even i/jj rows
      const int coO = coE ^ 32;                      // odd  i/jj rows (+4 hash)
      bf16x8 bfr[2], af[4];
      bfr[0] = *(const bf16x8*)&Bsl[(brow0) * 64 + coE];
      bfr[1] = *(const bf16x8*)&Bsl[(brow0 + 32) * 64 + coO];
      af[0] = *(const bf16x8*)&Asl[(arow0) * 64 + coE];
      af[1] = *(const bf16x8*)&Asl[(arow0 + 32) * 64 + coO];
      af[2] = *(const bf16x8*)&Asl[(arow0 + 64) * 64 + coE];
      af[3] = *(const bf16x8*)&Asl[(arow0 + 96) * 64 + coO];
#pragma unroll
      for (int i = 0; i < 4; ++i)
#pragma unroll
        for (int jj = 0; jj < 2; ++jj)
          acc[i][jj] = __builtin_amdgcn_mfma_f32_32x32x16_bf16(
              af[i], bfr[jj], acc[i][jj], 0, 0, 0);
    }
    __builtin_amdgcn_s_setprio(0);
  }
  __syncthreads();  // K-loop reads done before Ct overwrites staging LDS

  // ---- epilogue: two 128-col halves; Ct[256][132] reuses staging LDS ----
  unsigned short* Ct = &sm[0][0];
#pragma unroll 1
  for (int h = 0; h < 2; ++h) {
    const int slot = 2 * bn + h;  // 0..31 Q, 32..39 K, 40..47 V
    if ((wcol >> 1) == h) {       // waves owning this col half write acc
#pragma unroll
      for (int i = 0; i < 4; ++i)
#pragma unroll
        for (int jj = 0; jj < 2; ++jj) {
          int lc = (wcol & 1) * 64 + jj * 32 + l31;
          float bv = bias[slot * 128 + lc];
#pragma unroll
          for (int r = 0; r < 16; ++r) {
            int lrw = wrow * 128 + i * 32 + (r & 3) + 8 * (r >> 2) + 4 * lh;
            Ct[lrw * 132 + lc] = f2b(acc[i][jj][r] + bv);
          }
        }
    }
    __syncthreads();

    if (slot < 40) {
#pragma unroll 4
      for (int it = 0; it < 32; ++it) {
        int row = it * 8 + wave;  // 0..255
        int d = lane;
        float x1 = b2f(Ct[row * 132 + d]);
        float x2 = b2f(Ct[row * 132 + d + 64]);
        int s = bm * 256 + row;
        float2 cs = rtab[s * 64 + d];  // (cos, sin) precomputed
        float o1 = x1 * cs.x - x2 * cs.y;
        float o2 = x2 * cs.x + x1 * cs.y;
        unsigned short* dst;
        if (slot < 32)
          dst = Qb + ((size_t)slot * S_LEN + s) * HD;
        else
          dst = Kb + ((size_t)(slot - 32) * S_LEN + s) * HD;
        dst[d] = f2b(o1);
        dst[d + 64] = f2b(o2);
      }
    } else {
      // V: write transposed Vt[g][d][s], coalesced along s
      const int g = slot - 40;
      unsigned short* Vtg = Vt + (size_t)g * HD * S_LEN;  // [128][2048]
      const int dp = tid >> 3;         // d-pair 0..63
      const int sq = (tid & 7) << 5;   // s-eighth 0,32,..,224
      unsigned short buf0[32], buf1[32];
#pragma unroll
      for (int i = 0; i < 32; ++i) {
        unsigned int w = *(const unsigned int*)&Ct[(sq + i) * 132 + 2 * dp];
        buf0[i] = (unsigned short)(w & 0xffffu);
        buf1[i] = (unsigned short)(w >> 16);
      }
      const int s0 = bm * 256 + sq;
#pragma unroll
      for (int c = 0; c < 2; ++c) {
        unsigned short* dst = Vtg + (size_t)(2 * dp + c) * S_LEN + s0;
        const unsigned short* b = c ? buf1 : buf0;
#pragma unroll
        for (int q4 = 0; q4 < 4; ++q4)
          *(int4*)(dst + q4 * 8) = *(const int4*)(b + q4 * 8);
      }
    }
    __syncthreads();  // pass-h reads done before pass h+1 overwrites Ct
  }
}

// ---------------------------------------------------------------------------
// GEMM2: out = attnb[2048][4096](bf16) * WoT^T + bo (f32 out).
// BM=128 x BN=256 (grid 16x16 = 256 blocks = 1/CU), BK=64, 8 waves (2M x 4N,
// 64x64 per wave), dbuf 96KiB LDS, 32x32x16 MFMA, single barrier per K-tile.
// Generalized hash swizzle (r7). FROZEN.
// ---------------------------------------------------------------------------
__global__ __launch_bounds__(512, 2) void gemm2_kernel(
    const unsigned short* __restrict__ Ab16,
    const unsigned short* __restrict__ BT, const float* __restrict__ bias,
    float* __restrict__ C) {
  // [slot][ A 128x64 | B 256x64 ] bf16 = 2 x 48KiB = 96KiB
  __shared__ unsigned short sm[2][24576];

  const int tid = threadIdx.x;
  const int bn = blockIdx.x, bm = blockIdx.y;  // bn: N/256, bm: M/128
  const int lane = tid & 63, wave = tid >> 6;
  const int l31 = lane & 31, lh = lane >> 5;
  const int wrow = wave >> 2, wcol = wave & 3;  // 2M x 4N wave grid

  f32x16 acc[2][2];
#pragma unroll
  for (int i = 0; i < 2; ++i)
#pragma unroll
    for (int j = 0; j < 2; ++j)
#pragma unroll
      for (int r = 0; r < 16; ++r) acc[i][j][r] = 0.f;

  const int lr8 = lane >> 3, lc8 = lane & 7;
  const int baser = wave * 8 + lr8;
  const size_t swz = (size_t)((lc8 ^ lr8 ^ wave) << 3);
  const unsigned short* sA = Ab16 + (size_t)(bm * 128 + baser) * MDIM + swz;
  const unsigned short* sB = BT + (size_t)(bn * 256 + baser) * MDIM + swz;

  auto stage = [&](int slot, int k0) {
#pragma unroll
    for (int c = 0; c < 2; ++c)
      async_copy16(sA + (size_t)c * 64 * MDIM + k0,
                   &sm[slot][(c * 64 + wave * 8) * 64]);
#pragma unroll
    for (int c = 0; c < 4; ++c)
      async_copy16(sB + (size_t)c * 64 * MDIM + k0,
                   &sm[slot][8192 + (c * 64 + wave * 8) * 64]);
  };

  const int arow0 = wrow * 64 + l31;  // + i*32
  const int brow0 = wcol * 64 + l31;  // + jj*32
  const int base = (l31 & 7) ^ (l31 >> 3);

  stage(0, 0);  // prologue: K-tile 0 -> slot 0

#pragma unroll 1
  for (int kt = 0; kt < 64; ++kt) {
    const int p = kt & 1;
    asm volatile("s_waitcnt vmcnt(0)" ::: "memory");
    __builtin_amdgcn_s_barrier();
    __builtin_amdgcn_sched_barrier(0);

    if (kt < 63) stage(p ^ 1, (kt + 1) << 6);

    const unsigned short* Asl = &sm[p][0];
    const unsigned short* Bsl = &sm[p][8192];
    __builtin_amdgcn_s_setprio(1);
#pragma unroll
    for (int t = 0; t < 4; ++t) {
      const int coE = (((2 * t + lh) ^ base) << 3);
      const int coO = coE ^ 32;
      bf16x8 bfr[2], af[2];
      bfr[0] = *(const bf16x8*)&Bsl[(brow0) * 64 + coE];
      bfr[1] = *(const bf16x8*)&Bsl[(brow0 + 32) * 64 + coO];
      af[0] = *(const bf16x8*)&Asl[(arow0) * 64 + coE];
      af[1] = *(const bf16x8*)&Asl[(arow0 + 32) * 64 + coO];
#pragma unroll
      for (int i = 0; i < 2; ++i)
#pragma unroll
        for (int jj = 0; jj < 2; ++jj)
          acc[i][jj] = __builtin_amdgcn_mfma_f32_32x32x16_bf16(
              af[i], bfr[jj], acc[i][jj], 0, 0, 0);
    }
    __builtin_amdgcn_s_setprio(0);
  }

  // epilogue: direct f32 store with bias
#pragma unroll
  for (int i = 0; i < 2; ++i)
#pragma unroll
    for (int jj = 0; jj < 2; ++jj) {
      int gcol = bn * 256 + wcol * 64 + jj * 32 + l31;
      float bv = bias[gcol];
#pragma unroll
      for (int r = 0; r < 16; ++r) {
        int grow =
            bm * 128 + wrow * 64 + i * 32 + (r & 3) + 8 * (r >> 2) + 4 * lh;
        C[(size_t)grow * MDIM + gcol] = acc[i][jj][r] + bv;
      }
    }
}

// ---------------------------------------------------------------------------
// Flash attention + fused Wo transpose (round 11).
//
// Blocks [0,1024): causal GQA flash attention (unchanged r9 body).
// Blocks [1024,5120): transpose+convert Wo f32 -> WoT bf16 (64x64 tiles,
//   reusing the Ks LDS region as f32 staging — 16.6KB <= 32KB).
// Rationale: transpose(Wo) (~20-25us, HBM-bound) and flash (LDS/MFMA-bound,
// LPT-imbalanced tail) are independent — both depend only on gemm1 — but
// ran serially on one stream (events banned under graph capture). Fused,
// the HBM-bound transpose blocks backfill CUs as flash blocks drain.
//
// Occupancy note (fixes r10's wrong claim): flash LDS = 32+32+9 = 73KB =>
// 2 blocks/CU is the LDS cap; (256,3) was a no-op. Bound restored to (256,2).
//
// Flash: fixed-max softmax (exp(s*scale-12), causal mask on diagonal tile),
// Q in registers, K/V double-buffered LDS via global_load_lds (XOR-swizzled
// via pre-swizzled global source), one vmcnt(0)+barrier per KV-tile with
// post-barrier prefetch, Ps fence lgkmcnt-only, row-sums via ones-MFMA,
// 1D LPT grid.
// ---------------------------------------------------------------------------
__device__ __forceinline__ void stage_kv(const unsigned short* __restrict__ Kg,
                                         const unsigned short* __restrict__ Vg,
                                         int jtile, unsigned short* KsBuf,
                                         unsigned short* VsBuf, int wv,
                                         int lane) {
  const unsigned short* kg = Kg + (size_t)jtile * 64 * HD;
  const unsigned short* vg = Vg + jtile * 64;
#pragma unroll
  for (int it = 0; it < 4; ++it) {
    // K: 4 rows x 256B per copy; lane -> row base+(l>>4), chunk l&15
    int kr = wv * 16 + it * 4 + (lane >> 4);
    async_copy16(kg + (size_t)kr * HD + (((lane & 15) ^ (kr & 7)) << 3),
                 KsBuf + (wv * 16 + it * 4) * 128);
    // V: 8 rows x 128B per copy; lane -> row base+(l>>3), chunk l&7
    int vr = wv * 32 + it * 8 + (lane >> 3);
    async_copy16(vg + (size_t)vr * S_LEN + (((lane & 7) ^ (vr & 7)) << 3),
                 VsBuf + (wv * 32 + it * 8) * 64);
  }
}

__global__ __launch_bounds__(256, 2) void flash_kernel(
    const unsigned short* __restrict__ Qb, const unsigned short* __restrict__ Kb,
    const unsigned short* __restrict__ Vt, unsigned short* __restrict__ attnb,
    const float* __restrict__ Wo, unsigned short* __restrict__ WoT) {
  __shared__ __align__(16) unsigned short Ks[2][64 * 128];  // [krow][d] swz
  __shared__ __align__(16) unsigned short Vs[2][128 * 64];  // [d][kvpos] swz
  __shared__ __align__(16) unsigned short Ps[64 * 72];      // [qrow][kvpos]

  const int tid = threadIdx.x;
  const int bid = blockIdx.x;

  if (bid >= 1024) {
    // ---- Wo transpose branch: [4096][4096] f32 -> WoT [4096][4096] bf16 ----
    float* t = (float*)&Ks[0][0];  // 64*65*4 = 16640B staging (<= 32KB)
    const int tt = bid - 1024;           // 0..4095
    const int n0 = (tt & 63) << 6;       // n tile
    const int k0 = (tt >> 6) << 6;       // k tile
#pragma unroll
    for (int it = 0; it < 4; ++it) {
      int idx = it * 256 + tid;        // 0..1023
      int r = idx >> 4;                // k row 0..63
      int cq = idx & 15;               // float4 col group
      const float4 v =
          *(const float4*)(Wo + (size_t)(k0 + r) * MDIM + n0 + (cq << 2));
      t[r * 65 + (cq << 2) + 0] = v.x;
      t[r * 65 + (cq << 2) + 1] = v.y;
      t[r * 65 + (cq << 2) + 2] = v.z;
      t[r * 65 + (cq << 2) + 3] = v.w;
    }
    __syncthreads();
    const int n = tid >> 2, kk = (tid & 3) << 4;
    unsigned short o[16];
#pragma unroll
    for (int j = 0; j < 16; ++j) o[j] = f2b(t[(kk + j) * 65 + n]);
    *(int4*)(WoT + (size_t)(n0 + n) * MDIM + k0 + kk) = *(const int4*)&o[0];
    *(int4*)(WoT + (size_t)(n0 + n) * MDIM + k0 + kk + 8) =
        *(const int4*)&o[8];
    return;
  }

  // ---- flash attention branch ----
  const int h = bid & 31;
  const int qt = 31 - (bid >> 5);  // heavy tiles dispatch first (LPT)
  const int g = h >> 2;
  const int wv = tid >> 6, lane = tid & 63;
  const int lrow = lane & 15, quad = lane >> 4;
  const float scale = 0.08838834764831845f;  // 1/sqrt(128)

  const unsigned short* Qg = Qb + ((size_t)h * S_LEN + qt * 64) * HD;
  bf16x8 qf[4];
#pragma unroll
  for (int ks = 0; ks < 4; ++ks)
    qf[ks] = *(const bf16x8*)(Qg + (size_t)(wv * 16 + lrow) * HD + ks * 32 +
                              quad * 8);

  // all-ones bf16 B-fragment for row-sum MFMA
  bf16x8 ones;
#pragma unroll
  for (int i = 0; i < 8; ++i) ones[i] = (short)0x3F80;

  const unsigned short* Kg = Kb + (size_t)g * S_LEN * HD;   // [s][d]
  const unsigned short* Vg = Vt + (size_t)g * HD * S_LEN;   // [d][s]

  f32x4 l_acc = {0.f, 0.f, 0.f, 0.f};
  f32x4 o_acc[8];
#pragma unroll
  for (int jc = 0; jc < 8; ++jc) {
    f32x4 z = {0.f, 0.f, 0.f, 0.f};
    o_acc[jc] = z;
  }

  // prologue: stage tile 0 into buffer 0
  stage_kv(Kg, Vg, 0, &Ks[0][0], &Vs[0][0], wv, lane);

  for (int jt = 0; jt <= qt; ++jt) {
    const int cb = jt & 1;
    // own copies of tile jt are the only outstanding VMEM ops
    asm volatile("s_waitcnt vmcnt(0)" ::: "memory");
    __builtin_amdgcn_s_barrier();  // all waves' copies landed; all waves
                                   // done reading buf cb from iter jt-2
    __builtin_amdgcn_sched_barrier(0);

    if (jt < qt)  // prefetch next tile; flies under this iter's compute
      stage_kv(Kg, Vg, jt + 1, &Ks[cb ^ 1][0], &Vs[cb ^ 1][0], wv, lane);

    // S = Q K^T (wave's 16 rows x 64 cols)
    f32x4 s_acc[4];
#pragma unroll
    for (int j = 0; j < 4; ++j) {
      f32x4 z = {0.f, 0.f, 0.f, 0.f};
      s_acc[j] = z;
    }
#pragma unroll
    for (int ks = 0; ks < 4; ++ks)
#pragma unroll
      for (int j = 0; j < 4; ++j) {
        int row = j * 16 + lrow;
        bf16x8 bk = *(const bf16x8*)&Ks[cb][row * 128 +
                                           (((ks * 4 + quad) ^ (row & 7)) << 3)];
        s_acc[j] = __builtin_amdgcn_mfma_f32_16x16x32_bf16(qf[ks], bk,
                                                           s_acc[j], 0, 0, 0);
      }

    // fixed-max softmax: p = exp(s*scale - 12); mask only on diagonal tile
    if (jt == qt) {
#pragma unroll
      for (int r = 0; r < 4; ++r) {
        int grow = qt * 64 + wv * 16 + quad * 4 + r;
#pragma unroll
        for (int j = 0; j < 4; ++j) {
          int gcol = jt * 64 + j * 16 + lrow;
          float p =
              (gcol <= grow) ? __expf(s_acc[j][r] * scale - 12.0f) : 0.f;
          Ps[(wv * 16 + quad * 4 + r) * 72 + j * 16 + lrow] = f2b(p);
        }
      }
    } else {
#pragma unroll
      for (int r = 0; r < 4; ++r)
#pragma unroll
        for (int j = 0; j < 4; ++j) {
          float p = __expf(s_acc[j][r] * scale - 12.0f);
          Ps[(wv * 16 + quad * 4 + r) * 72 + j * 16 + lrow] = f2b(p);
        }
    }
    // Ps band is wave-private: LDS drain only (must NOT drain vmcnt — the
    // next tile's global_load_lds copies are in flight)
    asm volatile("s_waitcnt lgkmcnt(0)" ::: "memory");
    __builtin_amdgcn_sched_barrier(0);

    // O += P V (16 rows x 128 cols, K=64); l += P * ones
#pragma unroll
    for (int kk = 0; kk < 2; ++kk) {
      bf16x8 ap =
          *(const bf16x8*)&Ps[(wv * 16 + lrow) * 72 + kk * 32 + 8 * quad];
      l_acc = __builtin_amdgcn_mfma_f32_16x16x32_bf16(ap, ones, l_acc, 0, 0, 0);
#pragma unroll
      for (int jc = 0; jc < 8; ++jc) {
        int row = jc * 16 + lrow;
        bf16x8 bv = *(const bf16x8*)&Vs[cb][row * 64 +
                                            (((kk * 4 + quad) ^ (row & 7)) << 3)];
        o_acc[jc] = __builtin_amdgcn_mfma_f32_16x16x32_bf16(ap, bv, o_acc[jc],
                                                            0, 0, 0);
      }
    }
    __builtin_amdgcn_s_barrier();  // all waves done reading buf cb before
                                   // iter jt+1 issues copies into buf cb
  }

  // epilogue: O / l -> attnb[s][h*128+d] (bf16)
#pragma unroll
  for (int r = 0; r < 4; ++r) {
    float inv_l = 1.0f / l_acc[r];
    int row = qt * 64 + wv * 16 + quad * 4 + r;
#pragma unroll
    for (int jc = 0; jc < 8; ++jc) {
      int col = jc * 16 + lrow;
      attnb[(size_t)row * MDIM + h * HD + col] = f2b(o_acc[jc][r] * inv_l);
    }
  }
}

// ---------------------------------------------------------------------------
extern "C" void kernel_launch(void* const* d_in, const int* in_sizes, int n_in,
                              void* d_out, int out_size, void* d_ws,
                              size_t ws_size, hipStream_t stream) {
  const float* x = (const float*)d_in[0];
  const float* Wqkv = (const float*)d_in[1];
  const float* bqkv = (const float*)d_in[2];
  const float* Wo = (const float*)d_in[3];
  const float* bo = (const float*)d_in[4];
  float* out = (float*)d_out;

  unsigned char* ws = (unsigned char*)d_ws;
  // region A [0, 50331648): phase1 = WT (6144x4096 bf16);
  //                         phase2 = WoT (33554432) + attnb (16777216)
  unsigned short* WT = (unsigned short*)ws;
  unsigned short* WoT = (unsigned short*)ws;
  unsigned short* attnb = (unsigned short*)(ws + 33554432);
  // region B: Q/K head-major bf16, V transposed [g][d][s]
  unsigned short* Qb = (unsigned short*)(ws + 50331648);  // 32*2048*128
  unsigned short* Kb = (unsigned short*)(ws + 67108864);  // 8*2048*128
  unsigned short* Vt = (unsigned short*)(ws + 71303168);  // 8*128*2048
  // d_out scratch: xb (bf16 x) in [0,16MB); RoPE table in [16MB,17MB).
  // Both consumed before gemm2 overwrites d_out with the final output.
  unsigned short* xb = (unsigned short*)d_out;
  float2* rtab = (float2*)((unsigned char*)d_out + 16777216);

  // 0. fused prep: convert_x + rope table + transpose(Wqkv) -> WT
  prep_kernel<<<4096 + 512 + 6144, 256, 0, stream>>>(x, Wqkv, xb, rtab, WT);
  // 1. QKV GEMM with fused bias + RoPE + head split (V transposed)
  gemm1_kernel<<<dim3(NFUSED / 256, S_LEN / 256), 512, 0, stream>>>(
      xb, WT, bqkv, rtab, Qb, Kb, Vt);
  // 2. fused: causal GQA flash attention -> attnb bf16 (blocks 0..1023, LPT)
  //    + transpose(Wo) -> WoT (blocks 1024..5119; WT consumed by gemm1)
  flash_kernel<<<1024 + 4096, 256, 0, stream>>>(Qb, Kb, Vt, attnb, Wo, WoT);
  // 3. output projection (overwrites xb scratch region of d_out)
  gemm2_kernel<<<dim3(MDIM / 256, S_LEN / 128), 512, 0, stream>>>(attnb, WoT,
                                                                  bo, out);
}

// Round 13
// 457.728 us; speedup vs baseline: 1.0825x; 1.0006x over previous
//
#include <hip/hip_runtime.h>
#include <hip/hip_bf16.h>
#include <math.h>

#define S_LEN  2048
#define MDIM   4096
#define NHEADS 32
#define NKV    8
#define HD     128
#define KVDIM  1024
#define NFUSED (MDIM + 2 * KVDIM) /* 6144 */

typedef short bf16x8 __attribute__((ext_vector_type(8)));
typedef float f32x4 __attribute__((ext_vector_type(4)));
typedef float f32x16 __attribute__((ext_vector_type(16)));

__device__ __forceinline__ unsigned short f2b(float f) {
  union { float f; unsigned int u; } v; v.f = f;
  unsigned int r = v.u + 0x7FFFu + ((v.u >> 16) & 1u);
  return (unsigned short)(r >> 16);
}
__device__ __forceinline__ float b2f(unsigned short h) {
  union { unsigned int u; float f; } v; v.u = ((unsigned int)h) << 16;
  return v.f;
}

// async global->LDS, 16B per lane; lds dest = wave-uniform base + lane*16
__device__ __forceinline__ void async_copy16(const void* g, void* l) {
  __builtin_amdgcn_global_load_lds(
      (const __attribute__((address_space(1))) unsigned int*)g,
      (__attribute__((address_space(3))) unsigned int*)l, 16, 0, 0);
}

// ---------------------------------------------------------------------------
// Fused prep kernel: convert_x + rope_table + transpose(Wqkv) in ONE launch.
// Block partition: [0,4096) convert_x, [4096,4608) rope, [4608,10752)
// transpose Wqkv (n-tile = t%96, k-tile = t/96).
// ---------------------------------------------------------------------------
__global__ __launch_bounds__(256) void prep_kernel(
    const float* __restrict__ x, const float* __restrict__ Wqkv,
    unsigned short* __restrict__ xb, float2* __restrict__ rtab,
    unsigned short* __restrict__ WT) {
  __shared__ float t[64 * 65];  // used by the transpose branch only
  const int b = blockIdx.x;
  const int tid = threadIdx.x;

  if (b < 4096) {
    // ---- x f32 -> bf16 (one thread per 8 elements) ----
    size_t i = (size_t)b * 256 + tid;
    const float4 a = ((const float4*)x)[2 * i];
    const float4 c = ((const float4*)x)[2 * i + 1];
    unsigned short o[8] = {f2b(a.x), f2b(a.y), f2b(a.z), f2b(a.w),
                           f2b(c.x), f2b(c.y), f2b(c.z), f2b(c.w)};
    *(int4*)(xb + 8 * i) = *(const int4*)o;
  } else if (b < 4608) {
    // ---- RoPE table: rtab[s*64+d] = (cos,sin)(s * 50000^(-d/64)) ----
    int idx = (b - 4096) * 256 + tid;  // 0..131071
    int s = idx >> 6, d = idx & 63;
    float inv_freq = __expf(-0.16905903569f * (float)d);
    float ang = (float)s * inv_freq;
    rtab[idx] = make_float2(cosf(ang), sinf(ang));
  } else {
    // ---- transpose+convert Wqkv [4096][6144] f32 -> WT [6144][4096] bf16 ----
    const int tt = b - 4608;            // 0..6143
    const int n0 = (tt % 96) << 6;      // n tile
    const int k0 = (tt / 96) << 6;      // k tile
    const int K = MDIM, N = NFUSED;
#pragma unroll
    for (int it = 0; it < 4; ++it) {
      int idx = it * 256 + tid;        // 0..1023
      int r = idx >> 4;                // k row 0..63
      int cq = idx & 15;               // float4 col group
      const float4 v =
          *(const float4*)(Wqkv + (size_t)(k0 + r) * N + n0 + (cq << 2));
      t[r * 65 + (cq << 2) + 0] = v.x;
      t[r * 65 + (cq << 2) + 1] = v.y;
      t[r * 65 + (cq << 2) + 2] = v.z;
      t[r * 65 + (cq << 2) + 3] = v.w;
    }
    __syncthreads();
    const int n = tid >> 2, kk = (tid & 3) << 4;
    unsigned short o[16];
#pragma unroll
    for (int j = 0; j < 16; ++j) o[j] = f2b(t[(kk + j) * 65 + n]);
    *(int4*)(WT + (size_t)(n0 + n) * K + k0 + kk) = *(const int4*)&o[0];
    *(int4*)(WT + (size_t)(n0 + n) * K + k0 + kk + 8) = *(const int4*)&o[8];
  }
}

// ---------------------------------------------------------------------------
// GEMM1: fused = xb[2048][4096](bf16) * WT^T + bqkv, RoPE + head-split
// epilogue. 256x256 tile, BK=64, 8 waves (2M x 4N), dbuf 128KiB LDS,
// 32x32x16 MFMA, single vmcnt(0)+barrier per K-tile. FROZEN (122-125us).
// ---------------------------------------------------------------------------
__global__ __launch_bounds__(512, 2) void gemm1_kernel(
    const unsigned short* __restrict__ xb,
    const unsigned short* __restrict__ WT, const float* __restrict__ bias,
    const float2* __restrict__ rtab, unsigned short* __restrict__ Qb,
    unsigned short* __restrict__ Kb, unsigned short* __restrict__ Vt) {
  // [slot][ A 256x64 | B 256x64 ] bf16 = 2 x 64KiB = 128KiB
  __shared__ unsigned short sm[2][32768];

  const int tid = threadIdx.x;
  const int bn = blockIdx.x, bm = blockIdx.y;
  const int lane = tid & 63, wave = tid >> 6;
  const int l31 = lane & 31, lh = lane >> 5;
  const int wrow = wave >> 2, wcol = wave & 3;  // 2M x 4N wave grid

  f32x16 acc[4][2];
#pragma unroll
  for (int i = 0; i < 4; ++i)
#pragma unroll
    for (int j = 0; j < 2; ++j)
#pragma unroll
      for (int r = 0; r < 16; ++r) acc[i][j][r] = 0.f;

  // staging: each copy = 64 rows over 8 waves (8 rows/wave); lane ->
  // (row lr8, phys chunk lc8). hash(destrow)=lr8^wave -> src chunk below.
  const int lr8 = lane >> 3, lc8 = lane & 7;
  const int baser = wave * 8 + lr8;                    // tile row (+c*64)
  const size_t swz = (size_t)((lc8 ^ lr8 ^ wave) << 3);  // pre-swizzle
  const unsigned short* sA = xb + (size_t)(bm * 256 + baser) * MDIM + swz;
  const unsigned short* sB = WT + (size_t)(bn * 256 + baser) * MDIM + swz;

  auto stage = [&](int slot, int k0) {
#pragma unroll
    for (int c = 0; c < 4; ++c) {
      unsigned short* dA = &sm[slot][(c * 64 + wave * 8) * 64];
      unsigned short* dB = &sm[slot][16384 + (c * 64 + wave * 8) * 64];
      async_copy16(sA + (size_t)c * 64 * MDIM + k0, dA);
      async_copy16(sB + (size_t)c * 64 * MDIM + k0, dB);
    }
  };

  // fragment-read invariants
  const int arow0 = wrow * 128 + l31;  // + i*32
  const int brow0 = wcol * 64 + l31;   // + jj*32
  const int base = (l31 & 7) ^ (l31 >> 3);

  stage(0, 0);  // prologue: K-tile 0 -> slot 0

  for (int kt = 0; kt < 64; ++kt) {
    const int p = kt & 1;
    asm volatile("s_waitcnt vmcnt(0)" ::: "memory");
    __builtin_amdgcn_s_barrier();  // copies landed; slot p^1 free
    __builtin_amdgcn_sched_barrier(0);

    if (kt < 63) stage(p ^ 1, (kt + 1) << 6);  // flies under this compute

    const unsigned short* Asl = &sm[p][0];
    const unsigned short* Bsl = &sm[p][16384];
    __builtin_amdgcn_s_setprio(1);
#pragma unroll
    for (int t = 0; t < 4; ++t) {  // k-step of 16
      const int coE = (((2 * t + lh) ^ base) << 3);  // even i/jj rows
      const int coO = coE ^ 32;                      // odd  i/jj rows
      bf16x8 bfr[2], af[4];
      bfr[0] = *(const bf16x8*)&Bsl[(brow0) * 64 + coE];
      bfr[1] = *(const bf16x8*)&Bsl[(brow0 + 32) * 64 + coO];
      af[0] = *(const bf16x8*)&Asl[(arow0) * 64 + coE];
      af[1] = *(const bf16x8*)&Asl[(arow0 + 32) * 64 + coO];
      af[2] = *(const bf16x8*)&Asl[(arow0 + 64) * 64 + coE];
      af[3] = *(const bf16x8*)&Asl[(arow0 + 96) * 64 + coO];
#pragma unroll
      for (int i = 0; i < 4; ++i)
#pragma unroll
        for (int jj = 0; jj < 2; ++jj)
          acc[i][jj] = __builtin_amdgcn_mfma_f32_32x32x16_bf16(
              af[i], bfr[jj], acc[i][jj], 0, 0, 0);
    }
    __builtin_amdgcn_s_setprio(0);
  }
  __syncthreads();  // K-loop reads done before Ct overwrites staging LDS

  // ---- epilogue: two 128-col halves; Ct[256][132] reuses staging LDS ----
  unsigned short* Ct = &sm[0][0];
#pragma unroll 1
  for (int h = 0; h < 2; ++h) {
    const int slot = 2 * bn + h;  // 0..31 Q, 32..39 K, 40..47 V
    if ((wcol >> 1) == h) {       // waves owning this col half write acc
#pragma unroll
      for (int i = 0; i < 4; ++i)
#pragma unroll
        for (int jj = 0; jj < 2; ++jj) {
          int lc = (wcol & 1) * 64 + jj * 32 + l31;
          float bv = bias[slot * 128 + lc];
#pragma unroll
          for (int r = 0; r < 16; ++r) {
            int lrw = wrow * 128 + i * 32 + (r & 3) + 8 * (r >> 2) + 4 * lh;
            Ct[lrw * 132 + lc] = f2b(acc[i][jj][r] + bv);
          }
        }
    }
    __syncthreads();

    if (slot < 40) {
#pragma unroll 4
      for (int it = 0; it < 32; ++it) {
        int row = it * 8 + wave;  // 0..255
        int d = lane;
        float x1 = b2f(Ct[row * 132 + d]);
        float x2 = b2f(Ct[row * 132 + d + 64]);
        int s = bm * 256 + row;
        float2 cs = rtab[s * 64 + d];  // (cos, sin) precomputed
        float o1 = x1 * cs.x - x2 * cs.y;
        float o2 = x2 * cs.x + x1 * cs.y;
        unsigned short* dst;
        if (slot < 32)
          dst = Qb + ((size_t)slot * S_LEN + s) * HD;
        else
          dst = Kb + ((size_t)(slot - 32) * S_LEN + s) * HD;
        dst[d] = f2b(o1);
        dst[d + 64] = f2b(o2);
      }
    } else {
      // V: write transposed Vt[g][d][s], coalesced along s
      const int g = slot - 40;
      unsigned short* Vtg = Vt + (size_t)g * HD * S_LEN;  // [128][2048]
      const int dp = tid >> 3;         // d-pair 0..63
      const int sq = (tid & 7) << 5;   // s-eighth 0,32,..,224
      unsigned short buf0[32], buf1[32];
#pragma unroll
      for (int i = 0; i < 32; ++i) {
        unsigned int w = *(const unsigned int*)&Ct[(sq + i) * 132 + 2 * dp];
        buf0[i] = (unsigned short)(w & 0xffffu);
        buf1[i] = (unsigned short)(w >> 16);
      }
      const int s0 = bm * 256 + sq;
#pragma unroll
      for (int c = 0; c < 2; ++c) {
        unsigned short* dst = Vtg + (size_t)(2 * dp + c) * S_LEN + s0;
        const unsigned short* b = c ? buf1 : buf0;
#pragma unroll
        for (int q4 = 0; q4 < 4; ++q4)
          *(int4*)(dst + q4 * 8) = *(const int4*)(b + q4 * 8);
      }
    }
    __syncthreads();  // pass-h reads done before pass h+1 overwrites Ct
  }
}

// ---------------------------------------------------------------------------
// GEMM2: out = attnb[2048][4096](bf16) * WoT^T + bo (f32 out).
// BM=128 x BN=256 (grid 16x16 = 256 blocks = 1/CU), BK=64, 8 waves,
// dbuf 96KiB LDS, 32x32x16 MFMA, single barrier per K-tile. FROZEN.
// ---------------------------------------------------------------------------
__global__ __launch_bounds__(512, 2) void gemm2_kernel(
    const unsigned short* __restrict__ Ab16,
    const unsigned short* __restrict__ BT, const float* __restrict__ bias,
    float* __restrict__ C) {
  // [slot][ A 128x64 | B 256x64 ] bf16 = 2 x 48KiB = 96KiB
  __shared__ unsigned short sm[2][24576];

  const int tid = threadIdx.x;
  const int bn = blockIdx.x, bm = blockIdx.y;  // bn: N/256, bm: M/128
  const int lane = tid & 63, wave = tid >> 6;
  const int l31 = lane & 31, lh = lane >> 5;
  const int wrow = wave >> 2, wcol = wave & 3;  // 2M x 4N wave grid

  f32x16 acc[2][2];
#pragma unroll
  for (int i = 0; i < 2; ++i)
#pragma unroll
    for (int j = 0; j < 2; ++j)
#pragma unroll
      for (int r = 0; r < 16; ++r) acc[i][j][r] = 0.f;

  const int lr8 = lane >> 3, lc8 = lane & 7;
  const int baser = wave * 8 + lr8;
  const size_t swz = (size_t)((lc8 ^ lr8 ^ wave) << 3);
  const unsigned short* sA = Ab16 + (size_t)(bm * 128 + baser) * MDIM + swz;
  const unsigned short* sB = BT + (size_t)(bn * 256 + baser) * MDIM + swz;

  auto stage = [&](int slot, int k0) {
#pragma unroll
    for (int c = 0; c < 2; ++c)
      async_copy16(sA + (size_t)c * 64 * MDIM + k0,
                   &sm[slot][(c * 64 + wave * 8) * 64]);
#pragma unroll
    for (int c = 0; c < 4; ++c)
      async_copy16(sB + (size_t)c * 64 * MDIM + k0,
                   &sm[slot][8192 + (c * 64 + wave * 8) * 64]);
  };

  const int arow0 = wrow * 64 + l31;  // + i*32
  const int brow0 = wcol * 64 + l31;  // + jj*32
  const int base = (l31 & 7) ^ (l31 >> 3);

  stage(0, 0);  // prologue: K-tile 0 -> slot 0

#pragma unroll 1
  for (int kt = 0; kt < 64; ++kt) {
    const int p = kt & 1;
    asm volatile("s_waitcnt vmcnt(0)" ::: "memory");
    __builtin_amdgcn_s_barrier();
    __builtin_amdgcn_sched_barrier(0);

    if (kt < 63) stage(p ^ 1, (kt + 1) << 6);

    const unsigned short* Asl = &sm[p][0];
    const unsigned short* Bsl = &sm[p][8192];
    __builtin_amdgcn_s_setprio(1);
#pragma unroll
    for (int t = 0; t < 4; ++t) {
      const int coE = (((2 * t + lh) ^ base) << 3);
      const int coO = coE ^ 32;
      bf16x8 bfr[2], af[2];
      bfr[0] = *(const bf16x8*)&Bsl[(brow0) * 64 + coE];
      bfr[1] = *(const bf16x8*)&Bsl[(brow0 + 32) * 64 + coO];
      af[0] = *(const bf16x8*)&Asl[(arow0) * 64 + coE];
      af[1] = *(const bf16x8*)&Asl[(arow0 + 32) * 64 + coO];
#pragma unroll
      for (int i = 0; i < 2; ++i)
#pragma unroll
        for (int jj = 0; jj < 2; ++jj)
          acc[i][jj] = __builtin_amdgcn_mfma_f32_32x32x16_bf16(
              af[i], bfr[jj], acc[i][jj], 0, 0, 0);
    }
    __builtin_amdgcn_s_setprio(0);
  }

  // epilogue: direct f32 store with bias
#pragma unroll
  for (int i = 0; i < 2; ++i)
#pragma unroll
    for (int jj = 0; jj < 2; ++jj) {
      int gcol = bn * 256 + wcol * 64 + jj * 32 + l31;
      float bv = bias[gcol];
#pragma unroll
      for (int r = 0; r < 16; ++r) {
        int grow =
            bm * 128 + wrow * 64 + i * 32 + (r & 3) + 8 * (r >> 2) + 4 * lh;
        C[(size_t)grow * MDIM + gcol] = acc[i][jj][r] + bv;
      }
    }
}

// ---------------------------------------------------------------------------
// Flash attention (QBLK=128, round 12) + fused Wo transpose.
//
// Blocks [0,512): flash, QBLK=128: 4 waves x 32 q-rows each. vs QBLK=64:
// block-iters halve (16896 -> 8704), so K/V staging traffic, barriers, and
// per-output K/V ds_reads all halve — flash's dominant pipe is LDS reads.
// K/V single-buffered (Ks 16K + Vs 16K + Ps[128][72] 18.4K = 51.2KB -> 3
// blocks/CU capacity; 512-block grid -> 2 resident/CU): the in-block dbuf
// prefetch is replaced by cross-block overlap — while one block waits on
// its stage vmcnt(0), the co-resident block computes. Regs ~210 (qf 64 +
// o_acc 64 + s_acc 32 + l 8 + temps) < 256 -> 8 waves/CU, no spill.
// Causal mask: elementwise only on tiles jt >= 2*qt.
//
// Blocks [512,4608): transpose+convert Wo f32 -> WoT bf16 (64x64 tiles,
// f32 staging reuses smem; backfills CUs as flash's LPT tail drains).
// ---------------------------------------------------------------------------
__device__ __forceinline__ void stage_kv(const unsigned short* __restrict__ Kg,
                                         const unsigned short* __restrict__ Vg,
                                         int jtile, unsigned short* KsBuf,
                                         unsigned short* VsBuf, int wv,
                                         int lane) {
  const unsigned short* kg = Kg + (size_t)jtile * 64 * HD;
  const unsigned short* vg = Vg + jtile * 64;
#pragma unroll
  for (int it = 0; it < 4; ++it) {
    // K: 4 rows x 256B per copy; lane -> row base+(l>>4), chunk l&15
    int kr = wv * 16 + it * 4 + (lane >> 4);
    async_copy16(kg + (size_t)kr * HD + (((lane & 15) ^ (kr & 7)) << 3),
                 KsBuf + (wv * 16 + it * 4) * 128);
    // V: 8 rows x 128B per copy; lane -> row base+(l>>3), chunk l&7
    int vr = wv * 32 + it * 8 + (lane >> 3);
    async_copy16(vg + (size_t)vr * S_LEN + (((lane & 7) ^ (vr & 7)) << 3),
                 VsBuf + (wv * 32 + it * 8) * 64);
  }
}

__global__ __launch_bounds__(256, 2) void flash_kernel(
    const unsigned short* __restrict__ Qb, const unsigned short* __restrict__ Kb,
    const unsigned short* __restrict__ Vt, unsigned short* __restrict__ attnb,
    const float* __restrict__ Wo, unsigned short* __restrict__ WoT) {
  // Ks [64][128] swz | Vs [128][64] swz | Ps [128][72] = 51200 B
  __shared__ __align__(16) unsigned short smem[25600];
  unsigned short* Ks = smem;          // 8192 shorts
  unsigned short* Vs = smem + 8192;   // 8192 shorts
  unsigned short* Ps = smem + 16384;  // 9216 shorts

  const int tid = threadIdx.x;
  const int bid = blockIdx.x;

  if (bid >= 512) {
    // ---- Wo transpose branch: [4096][4096] f32 -> WoT bf16 ----
    float* t = (float*)smem;  // 64*65*4 = 16640B staging (<= 51200)
    const int tt = bid - 512;            // 0..4095
    const int n0 = (tt & 63) << 6;       // n tile
    const int k0 = (tt >> 6) << 6;       // k tile
#pragma unroll
    for (int it = 0; it < 4; ++it) {
      int idx = it * 256 + tid;        // 0..1023
      int r = idx >> 4;                // k row 0..63
      int cq = idx & 15;               // float4 col group
      const float4 v =
          *(const float4*)(Wo + (size_t)(k0 + r) * MDIM + n0 + (cq << 2));
      t[r * 65 + (cq << 2) + 0] = v.x;
      t[r * 65 + (cq << 2) + 1] = v.y;
      t[r * 65 + (cq << 2) + 2] = v.z;
      t[r * 65 + (cq << 2) + 3] = v.w;
    }
    __syncthreads();
    const int n = tid >> 2, kk = (tid & 3) << 4;
    unsigned short o[16];
#pragma unroll
    for (int j = 0; j < 16; ++j) o[j] = f2b(t[(kk + j) * 65 + n]);
    *(int4*)(WoT + (size_t)(n0 + n) * MDIM + k0 + kk) = *(const int4*)&o[0];
    *(int4*)(WoT + (size_t)(n0 + n) * MDIM + k0 + kk + 8) =
        *(const int4*)&o[8];
    return;
  }

  // ---- flash attention branch ----
  const int h = bid & 31;
  const int qt = 15 - (bid >> 5);  // q-tile of 128 rows; heavy first (LPT)
  const int g = h >> 2;
  const int wv = tid >> 6, lane = tid & 63;
  const int lrow = lane & 15, quad = lane >> 4;
  const float scale = 0.08838834764831845f;  // 1/sqrt(128)

  const unsigned short* Qg = Qb + ((size_t)h * S_LEN + qt * 128) * HD;
  bf16x8 qf[2][4];  // [row-tile][k-slice]
#pragma unroll
  for (int rt = 0; rt < 2; ++rt)
#pragma unroll
    for (int ks = 0; ks < 4; ++ks)
      qf[rt][ks] = *(const bf16x8*)(Qg +
                                    (size_t)(wv * 32 + rt * 16 + lrow) * HD +
                                    ks * 32 + quad * 8);

  // all-ones bf16 B-fragment for row-sum MFMA
  bf16x8 ones;
#pragma unroll
  for (int i = 0; i < 8; ++i) ones[i] = (short)0x3F80;

  const unsigned short* Kg = Kb + (size_t)g * S_LEN * HD;   // [s][d]
  const unsigned short* Vg = Vt + (size_t)g * HD * S_LEN;   // [d][s]

  f32x4 l_acc[2];
  f32x4 o_acc[2][8];
#pragma unroll
  for (int rt = 0; rt < 2; ++rt) {
    f32x4 z = {0.f, 0.f, 0.f, 0.f};
    l_acc[rt] = z;
#pragma unroll
    for (int jc = 0; jc < 8; ++jc) o_acc[rt][jc] = z;
  }

  const int ntiles = 2 * qt + 2;
  for (int jt = 0; jt < ntiles; ++jt) {
    // all waves done reading previous tile (loop-end barrier), stage jt
    stage_kv(Kg, Vg, jt, Ks, Vs, wv, lane);
    asm volatile("s_waitcnt vmcnt(0)" ::: "memory");
    __builtin_amdgcn_s_barrier();  // copies landed (stall covered by the
                                   // co-resident block's compute)
    __builtin_amdgcn_sched_barrier(0);

    // S = Q K^T (wave's 32 rows x 64 cols); bk shared across row-tiles
    f32x4 s_acc[2][4];
#pragma unroll
    for (int rt = 0; rt < 2; ++rt)
#pragma unroll
      for (int j = 0; j < 4; ++j) {
        f32x4 z = {0.f, 0.f, 0.f, 0.f};
        s_acc[rt][j] = z;
      }
#pragma unroll
    for (int ks = 0; ks < 4; ++ks)
#pragma unroll
      for (int j = 0; j < 4; ++j) {
        int row = j * 16 + lrow;
        bf16x8 bk = *(const bf16x8*)&Ks[row * 128 +
                                        (((ks * 4 + quad) ^ (row & 7)) << 3)];
        s_acc[0][j] = __builtin_amdgcn_mfma_f32_16x16x32_bf16(
            qf[0][ks], bk, s_acc[0][j], 0, 0, 0);
        s_acc[1][j] = __builtin_amdgcn_mfma_f32_16x16x32_bf16(
            qf[1][ks], bk, s_acc[1][j], 0, 0, 0);
      }

    // fixed-max softmax: p = exp(s*scale - 12); mask only when jt >= 2*qt
    if (jt >= 2 * qt) {
#pragma unroll
      for (int rt = 0; rt < 2; ++rt)
#pragma unroll
        for (int r = 0; r < 4; ++r) {
          int grow = qt * 128 + wv * 32 + rt * 16 + quad * 4 + r;
#pragma unroll
          for (int j = 0; j < 4; ++j) {
            int gcol = jt * 64 + j * 16 + lrow;
            float p =
                (gcol <= grow) ? __expf(s_acc[rt][j][r] * scale - 12.0f) : 0.f;
            Ps[(wv * 32 + rt * 16 + quad * 4 + r) * 72 + j * 16 + lrow] =
                f2b(p);
          }
        }
    } else {
#pragma unroll
      for (int rt = 0; rt < 2; ++rt)
#pragma unroll
        for (int r = 0; r < 4; ++r)
#pragma unroll
          for (int j = 0; j < 4; ++j) {
            float p = __expf(s_acc[rt][j][r] * scale - 12.0f);
            Ps[(wv * 32 + rt * 16 + quad * 4 + r) * 72 + j * 16 + lrow] =
                f2b(p);
          }
    }
    // Ps band is wave-private: LDS drain only
    asm volatile("s_waitcnt lgkmcnt(0)" ::: "memory");
    __builtin_amdgcn_sched_barrier(0);

    // O += P V (32 rows x 128 cols, K=64); l += P * ones; bv shared across rt
#pragma unroll
    for (int kk = 0; kk < 2; ++kk) {
      bf16x8 ap0 = *(const bf16x8*)&Ps[(wv * 32 + lrow) * 72 + kk * 32 +
                                       8 * quad];
      bf16x8 ap1 = *(const bf16x8*)&Ps[(wv * 32 + 16 + lrow) * 72 + kk * 32 +
                                       8 * quad];
      l_acc[0] =
          __builtin_amdgcn_mfma_f32_16x16x32_bf16(ap0, ones, l_acc[0], 0, 0, 0);
      l_acc[1] =
          __builtin_amdgcn_mfma_f32_16x16x32_bf16(ap1, ones, l_acc[1], 0, 0, 0);
#pragma unroll
      for (int jc = 0; jc < 8; ++jc) {
        int row = jc * 16 + lrow;
        bf16x8 bv = *(const bf16x8*)&Vs[row * 64 +
                                        (((kk * 4 + quad) ^ (row & 7)) << 3)];
        o_acc[0][jc] = __builtin_amdgcn_mfma_f32_16x16x32_bf16(
            ap0, bv, o_acc[0][jc], 0, 0, 0);
        o_acc[1][jc] = __builtin_amdgcn_mfma_f32_16x16x32_bf16(
            ap1, bv, o_acc[1][jc], 0, 0, 0);
      }
    }
    __builtin_amdgcn_s_barrier();  // all waves done reading Ks/Vs before
                                   // next iter's stage overwrites them
  }

  // epilogue: O / l -> attnb[s][h*128+d] (bf16)
#pragma unroll
  for (int rt = 0; rt < 2; ++rt)
#pragma unroll
    for (int r = 0; r < 4; ++r) {
      float inv_l = 1.0f / l_acc[rt][r];
      int row = qt * 128 + wv * 32 + rt * 16 + quad * 4 + r;
#pragma unroll
      for (int jc = 0; jc < 8; ++jc) {
        int col = jc * 16 + lrow;
        attnb[(size_t)row * MDIM + h * HD + col] =
            f2b(o_acc[rt][jc][r] * inv_l);
      }
    }
}

// ---------------------------------------------------------------------------
extern "C" void kernel_launch(void* const* d_in, const int* in_sizes, int n_in,
                              void* d_out, int out_size, void* d_ws,
                              size_t ws_size, hipStream_t stream) {
  const float* x = (const float*)d_in[0];
  const float* Wqkv = (const float*)d_in[1];
  const float* bqkv = (const float*)d_in[2];
  const float* Wo = (const float*)d_in[3];
  const float* bo = (const float*)d_in[4];
  float* out = (float*)d_out;

  unsigned char* ws = (unsigned char*)d_ws;
  // region A [0, 50331648): phase1 = WT (6144x4096 bf16);
  //                         phase2 = WoT (33554432) + attnb (16777216)
  unsigned short* WT = (unsigned short*)ws;
  unsigned short* WoT = (unsigned short*)ws;
  unsigned short* attnb = (unsigned short*)(ws + 33554432);
  // region B: Q/K head-major bf16, V transposed [g][d][s]
  unsigned short* Qb = (unsigned short*)(ws + 50331648);  // 32*2048*128
  unsigned short* Kb = (unsigned short*)(ws + 67108864);  // 8*2048*128
  unsigned short* Vt = (unsigned short*)(ws + 71303168);  // 8*128*2048
  // d_out scratch: xb (bf16 x) in [0,16MB); RoPE table in [16MB,17MB).
  unsigned short* xb = (unsigned short*)d_out;
  float2* rtab = (float2*)((unsigned char*)d_out + 16777216);

  // 0. fused prep: convert_x + rope table + transpose(Wqkv) -> WT
  prep_kernel<<<4096 + 512 + 6144, 256, 0, stream>>>(x, Wqkv, xb, rtab, WT);
  // 1. QKV GEMM with fused bias + RoPE + head split (V transposed)
  gemm1_kernel<<<dim3(NFUSED / 256, S_LEN / 256), 512, 0, stream>>>(
      xb, WT, bqkv, rtab, Qb, Kb, Vt);
  // 2. fused: causal GQA flash attention QBLK=128 (blocks 0..511, LPT)
  //    + transpose(Wo) -> WoT (blocks 512..4607; WT consumed by gemm1)
  flash_kernel<<<512 + 4096, 256, 0, stream>>>(Qb, Kb, Vt, attnb, Wo, WoT);
  // 3. output projection (overwrites xb scratch region of d_out)
  gemm2_kernel<<<dim3(MDIM / 256, S_LEN / 128), 512, 0, stream>>>(attnb, WoT,
                                                                  bo, out);
}